// Round 10
// baseline (14797.952 us; speedup 1.0000x reference)
//
#include <hip/hip_runtime.h>
#include <math.h>

#define N_   3072
#define D_   4
#define M_   512
#define NPAD 3200
#define NB   128
#define NBLK (NPAD/NB)   // 25
#define MBLK (M_/NB)     // 4
#define JITTER_ 0.05f
#define CBORD 32768.0f

// ============================================================================
// syrk64 engine: A[gr0..+64, gc0..+64] -= P_r P_c^T over cols [k0,k0+128).
// 256 threads (lt), valid-masked (barriers unconditional, block-wide).
// ============================================================================
__device__ void syrk64(float* A, int lda, int gr0, int gc0, int k0, int valid,
                       float* As, float* Bs, int lt) {
  const int tx = lt & 15, ty = lt >> 4;
  float acc[4][4];
  #pragma unroll
  for (int i=0;i<4;++i){acc[i][0]=0.f;acc[i][1]=0.f;acc[i][2]=0.f;acc[i][3]=0.f;}
  for (int ks = 0; ks < NB; ks += 32) {
    __syncthreads();
    if (valid) {
      for (int t = lt; t < 64*8; t += 256) {
        int rr = t >> 3, qq = t & 7;
        float4 v = *(const float4*)&A[(size_t)(gr0+rr)*lda + k0 + ks + qq*4];
        As[(qq*4+0)*68+rr]=v.x; As[(qq*4+1)*68+rr]=v.y;
        As[(qq*4+2)*68+rr]=v.z; As[(qq*4+3)*68+rr]=v.w;
        float4 w = *(const float4*)&A[(size_t)(gc0+rr)*lda + k0 + ks + qq*4];
        Bs[(qq*4+0)*68+rr]=w.x; Bs[(qq*4+1)*68+rr]=w.y;
        Bs[(qq*4+2)*68+rr]=w.z; Bs[(qq*4+3)*68+rr]=w.w;
      }
    }
    __syncthreads();
    if (valid) {
      #pragma unroll
      for (int kk = 0; kk < 32; ++kk) {
        float a[4], b[4];
        *(float4*)a = *(const float4*)&As[kk*68 + ty*4];
        *(float4*)b = *(const float4*)&Bs[kk*68 + tx*4];
        #pragma unroll
        for (int i=0;i<4;++i)
          #pragma unroll
          for (int u=0;u<4;++u) acc[i][u] += a[i]*b[u];
      }
    }
  }
  if (valid) {
    #pragma unroll
    for (int i=0;i<4;++i) {
      size_t off = (size_t)(gr0 + ty*4 + i)*lda + gc0 + tx*4;
      float4 v = *(const float4*)&A[off];
      v.x -= acc[i][0]; v.y -= acc[i][1]; v.z -= acc[i][2]; v.w -= acc[i][3];
      *(float4*)&A[off] = v;
    }
  }
}

// ============================================================================
// panel_duty: 512 threads, 64-granular potrf of 128-block at dj=bpot*NB.
//   LP = SM[0..8448)  : left panel 128 rows x 64 cols, col-major stride 132
//   DS = SM[8448..12800): diag2 64x64, col-major stride 68 (also presub As/Bs,
//                         also inverse R buffer)
// Sequence: load LP -> staged presub (panel k) -> factor LP -> store ->
//   load DS -> unstaged presub -> DS -= L21 L21^T -> factor DS -> store ->
//   logsum -> [doInv] W11 (LDS R at 8448) -> Tinv; T=L21*W11 (R); W22 inv
//   (R2 at 0, L22 from global); W21=-W22*T -> Tinv.
// ============================================================================
__device__ void panel_duty(float* A, int lda, int bpot, int presub, int doInv,
                           float* Tinv, float* logsum, int slot, int limit,
                           float* SM, float* pivd) {
  const int tid = threadIdx.x;
  const int dj = bpot * NB;
  float* LP = SM;
  // ---- load LP (rows dj..dj+128, cols dj..dj+64), lower part ----
  for (int t = tid; t < 64*NB; t += 512) {
    int r = t >> 6, c = t & 63;
    LP[c*132 + r] = (c <= r) ? A[(size_t)(dj+r)*lda + dj + c] : 0.f;
  }
  if (presub) {
    const int p0 = dj - NB;
    float* As = SM + 8448; float* Bs = As + 2176;
    const int tx = tid & 15, ty = tid >> 4;  // ty 0..31
    for (int sr = 0; sr < 2; ++sr) {
      float acc[2][4];
      #pragma unroll
      for (int i=0;i<2;++i){acc[i][0]=0.f;acc[i][1]=0.f;acc[i][2]=0.f;acc[i][3]=0.f;}
      for (int ks = 0; ks < NB; ks += 32) {
        __syncthreads();
        for (int t = tid; t < 64*8; t += 512) {
          int rr = t >> 3, qq = t & 7;
          float4 v = *(const float4*)&A[(size_t)(dj+sr*64+rr)*lda + p0 + ks + qq*4];
          As[(qq*4+0)*68+rr]=v.x; As[(qq*4+1)*68+rr]=v.y;
          As[(qq*4+2)*68+rr]=v.z; As[(qq*4+3)*68+rr]=v.w;
          float4 w = *(const float4*)&A[(size_t)(dj+rr)*lda + p0 + ks + qq*4];
          Bs[(qq*4+0)*68+rr]=w.x; Bs[(qq*4+1)*68+rr]=w.y;
          Bs[(qq*4+2)*68+rr]=w.z; Bs[(qq*4+3)*68+rr]=w.w;
        }
        __syncthreads();
        #pragma unroll
        for (int kk = 0; kk < 32; ++kk) {
          float a0 = As[kk*68 + ty*2], a1 = As[kk*68 + ty*2 + 1];
          float b[4];
          *(float4*)b = *(const float4*)&Bs[kk*68 + tx*4];
          #pragma unroll
          for (int u=0;u<4;++u) { acc[0][u] += a0*b[u]; acc[1][u] += a1*b[u]; }
        }
      }
      #pragma unroll
      for (int i=0;i<2;++i)
        #pragma unroll
        for (int u=0;u<4;++u) {
          int rr = sr*64 + ty*2 + i, cc = tx*4 + u;
          if (cc <= rr) LP[cc*132 + rr] -= acc[i][u];
        }
    }
  }
  __syncthreads();
  // ---- factor LP: cols 0..63 over 128 rows, 2 panels of 32, raw pivots ----
  #pragma unroll
  for (int p = 0; p < 2; ++p) {
    const int pc0 = p*32, pc1 = pc0 + 32;
    for (int j = pc0; j < pc1; ++j) {
      float dd = fmaxf(LP[j*132 + j], 1e-30f);
      if (tid == 0) pivd[j] = dd;
      float rd = 1.0f / dd;
      int wn = pc1 - 1 - j;
      for (int t = tid; t < wn*NB; t += 512) {
        int c = j + 1 + (t >> 7);
        int i = t & 127;
        if (i >= c) LP[c*132 + i] -= LP[j*132 + i] * LP[j*132 + c] * rd;
      }
      __syncthreads();
    }
    for (int t = tid; t < 32*NB; t += 512) {
      int jc = pc0 + (t >> 7), i = t & 127;
      float dd = pivd[jc];
      if (i > jc)       LP[jc*132 + i] *= rsqrtf(dd);
      else if (i == jc) LP[jc*132 + i] = sqrtf(dd);
    }
    __syncthreads();
    if (p == 0) {
      // rank-32 trailing on cols 32..63, rows 32..127, register-tiled 4x4
      for (int t = tid; t < 24*8; t += 512) {
        int tr = t >> 3, tc = t & 7;
        int i0 = 32 + tr*4, c0 = 32 + tc*4;
        if (i0 + 3 < c0) continue;
        float acc2[4][4];
        #pragma unroll
        for (int i=0;i<4;++i){acc2[i][0]=0.f;acc2[i][1]=0.f;acc2[i][2]=0.f;acc2[i][3]=0.f;}
        #pragma unroll
        for (int jj = 0; jj < 32; ++jj) {
          float av[4], bv[4];
          *(float4*)av = *(const float4*)&LP[jj*132 + i0];
          *(float4*)bv = *(const float4*)&LP[jj*132 + c0];
          #pragma unroll
          for (int i=0;i<4;++i)
            #pragma unroll
            for (int u=0;u<4;++u) acc2[i][u] += av[i]*bv[u];
        }
        #pragma unroll
        for (int i=0;i<4;++i)
          #pragma unroll
          for (int u=0;u<4;++u) {
            int rr = i0+i, cc = c0+u;
            if (cc <= rr) LP[cc*132 + rr] -= acc2[i][u];
          }
      }
      __syncthreads();
    }
  }
  // ---- store LP ----
  for (int t = tid; t < 64*NB; t += 512) {
    int r = t >> 6, c = t & 63;
    if (c <= r) A[(size_t)(dj+r)*lda + dj + c] = LP[c*132 + r];
  }
  __syncthreads();
  // ---- DS: load diag2 ----
  float* DS = SM + 8448;
  for (int t = tid; t < 64*64; t += 512) {
    int r = t >> 6, c = t & 63;
    DS[c*68 + r] = (c <= r) ? A[(size_t)(dj+64+r)*lda + dj+64 + c] : 0.f;
  }
  __syncthreads();
  {
    const int tx = tid & 15, ty = tid >> 4;
    const int r0 = ty*2, c0 = tx*4;
    float acc[2][4];
    #pragma unroll
    for (int i=0;i<2;++i){acc[i][0]=0.f;acc[i][1]=0.f;acc[i][2]=0.f;acc[i][3]=0.f;}
    if (presub) {
      const int p0 = dj - NB;
      for (int kk = 0; kk < NB; kk += 4) {
        float4 a0 = *(const float4*)&A[(size_t)(dj+64+r0)*lda + p0 + kk];
        float4 a1 = *(const float4*)&A[(size_t)(dj+64+r0+1)*lda + p0 + kk];
        #pragma unroll
        for (int u=0;u<4;++u) {
          float4 b = *(const float4*)&A[(size_t)(dj+64+c0+u)*lda + p0 + kk];
          acc[0][u] += a0.x*b.x + a0.y*b.y + a0.z*b.z + a0.w*b.w;
          acc[1][u] += a1.x*b.x + a1.y*b.y + a1.z*b.z + a1.w*b.w;
        }
      }
    }
    // + L21 L21^T from LDS LP (rows 64..127)
    for (int kk = 0; kk < 64; ++kk) {
      float a0 = LP[kk*132 + 64 + r0], a1 = LP[kk*132 + 64 + r0 + 1];
      float b0 = LP[kk*132 + 64 + c0],     b1 = LP[kk*132 + 64 + c0 + 1];
      float b2 = LP[kk*132 + 64 + c0 + 2], b3 = LP[kk*132 + 64 + c0 + 3];
      acc[0][0]+=a0*b0; acc[0][1]+=a0*b1; acc[0][2]+=a0*b2; acc[0][3]+=a0*b3;
      acc[1][0]+=a1*b0; acc[1][1]+=a1*b1; acc[1][2]+=a1*b2; acc[1][3]+=a1*b3;
    }
    #pragma unroll
    for (int i=0;i<2;++i)
      #pragma unroll
      for (int u=0;u<4;++u) {
        int rr = r0+i, cc = c0+u;
        if (cc <= rr) DS[cc*68 + rr] -= acc[i][u];
      }
  }
  __syncthreads();
  // ---- factor DS (64), 2 panels of 32 ----
  #pragma unroll
  for (int p = 0; p < 2; ++p) {
    const int pc0 = p*32, pc1 = pc0 + 32;
    for (int j = pc0; j < pc1; ++j) {
      float dd = fmaxf(DS[j*68 + j], 1e-30f);
      if (tid == 0) pivd[64 + j] = dd;
      float rd = 1.0f / dd;
      int wn = pc1 - 1 - j;
      for (int t = tid; t < wn*64; t += 512) {
        int c = j + 1 + (t >> 6);
        int i = t & 63;
        if (i >= c) DS[c*68 + i] -= DS[j*68 + i] * DS[j*68 + c] * rd;
      }
      __syncthreads();
    }
    for (int t = tid; t < 32*64; t += 512) {
      int jc = pc0 + (t >> 6), i = t & 63;
      float dd = pivd[64 + jc];
      if (i > jc)       DS[jc*68 + i] *= rsqrtf(dd);
      else if (i == jc) DS[jc*68 + i] = sqrtf(dd);
    }
    __syncthreads();
    if (p == 0) {
      for (int t = tid; t < 8*8; t += 512) {
        int tr = t >> 3, tc = t & 7;
        int i0 = 32 + tr*4, c0 = 32 + tc*4;
        if (i0 + 3 < c0) continue;
        float acc2[4][4];
        #pragma unroll
        for (int i=0;i<4;++i){acc2[i][0]=0.f;acc2[i][1]=0.f;acc2[i][2]=0.f;acc2[i][3]=0.f;}
        #pragma unroll
        for (int jj = 0; jj < 32; ++jj) {
          float av[4], bv[4];
          *(float4*)av = *(const float4*)&DS[jj*68 + i0];
          *(float4*)bv = *(const float4*)&DS[jj*68 + c0];
          #pragma unroll
          for (int i=0;i<4;++i)
            #pragma unroll
            for (int u=0;u<4;++u) acc2[i][u] += av[i]*bv[u];
        }
        #pragma unroll
        for (int i=0;i<4;++i)
          #pragma unroll
          for (int u=0;u<4;++u) {
            int rr = i0+i, cc = c0+u;
            if (cc <= rr) DS[cc*68 + rr] -= acc2[i][u];
          }
      }
      __syncthreads();
    }
  }
  // ---- store DS ----
  for (int t = tid; t < 64*64; t += 512) {
    int r = t >> 6, c = t & 63;
    if (c <= r) A[(size_t)(dj+64+r)*lda + dj+64 + c] = DS[c*68 + r];
  }
  __syncthreads();
  // ---- logsum (raw pivots, 0.5*log) ----
  {
    float lg = 0.f;
    if (tid < NB) {
      int g = dj + tid;
      if (g < limit) lg = 0.5f * logf(pivd[tid]);
    }
    for (int o = 32; o; o >>= 1) lg += __shfl_down(lg, o);
    int wv = tid >> 6;
    if ((tid & 63) == 0 && wv < 2) logsum[slot*2 + wv] = lg;
  }
  if (!doInv) return;
  // ---- W11 = inv(L11) from LP, R buffer over DS region ----
  float* R = SM + 8448;   // stride 66
  for (int t = tid; t < 64*64; t += 512) {
    int i = t >> 6, c = t & 63;
    R[i*66 + c] = (i == c) ? 1.f : 0.f;
  }
  __syncthreads();
  for (int j = 0; j < 64; ++j) {
    float dinv = 1.0f / LP[j*132 + j];
    int nc = j + 1, ni = 63 - j;
    for (int t = tid; t < ni*nc; t += 512) {
      int i = j + 1 + t / nc, c = t - (t / nc)*nc;
      R[i*66 + c] -= LP[j*132 + i] * R[j*66 + c] * dinv;
    }
    __syncthreads();
  }
  for (int t = tid; t < 64*64; t += 512) {
    int i = t >> 6, c = t & 63;
    if (c <= i) R[i*66 + c] *= 1.0f / LP[i*132 + i];
  }
  __syncthreads();
  // write W11 rows (+ zero right half)
  for (int t = tid; t < 64*NB; t += 512) {
    int i = t >> 7, c = t & 127;
    Tinv[i*NB + c] = (c < 64) ? R[i*66 + c] : 0.f;
  }
  __syncthreads();
  // ---- T = L21 * W11 (read W11 from global Tinv), into R ----
  {
    const int tx = tid & 15, ty = tid >> 4;
    const int r0 = ty*2, c0 = tx*4;
    float acc[2][4];
    #pragma unroll
    for (int i=0;i<2;++i){acc[i][0]=0.f;acc[i][1]=0.f;acc[i][2]=0.f;acc[i][3]=0.f;}
    for (int k = 0; k < 64; ++k) {
      float a0 = LP[k*132 + 64 + r0], a1 = LP[k*132 + 64 + r0 + 1];
      float4 b = *(const float4*)&Tinv[k*NB + c0];
      acc[0][0]+=a0*b.x; acc[0][1]+=a0*b.y; acc[0][2]+=a0*b.z; acc[0][3]+=a0*b.w;
      acc[1][0]+=a1*b.x; acc[1][1]+=a1*b.y; acc[1][2]+=a1*b.z; acc[1][3]+=a1*b.w;
    }
    __syncthreads();   // all reads of R (none) / ensure Tinv reads done before R overwrite
    #pragma unroll
    for (int i=0;i<2;++i)
      #pragma unroll
      for (int u=0;u<4;++u) R[(r0+i)*66 + c0+u] = acc[i][u];
  }
  __syncthreads();
  // ---- W22 = inv(L22) reading L22 from GLOBAL, R2 buffer over LP region ----
  float* R2 = SM;   // stride 66
  for (int t = tid; t < 64*64; t += 512) {
    int i = t >> 6, c = t & 63;
    R2[i*66 + c] = (i == c) ? 1.f : 0.f;
  }
  __syncthreads();
  for (int j = 0; j < 64; ++j) {
    float dinv = 1.0f / A[(size_t)(dj+64+j)*lda + dj+64 + j];
    int nc = j + 1, ni = 63 - j;
    for (int t = tid; t < ni*nc; t += 512) {
      int i = j + 1 + t / nc, c = t - (t / nc)*nc;
      R2[i*66 + c] -= A[(size_t)(dj+64+i)*lda + dj+64 + j] * R2[j*66 + c] * dinv;
    }
    __syncthreads();
  }
  for (int t = tid; t < 64*64; t += 512) {
    int i = t >> 6, c = t & 63;
    if (c <= i) R2[i*66 + c] *= 1.0f / A[(size_t)(dj+64+i)*lda + dj+64 + i];
  }
  __syncthreads();
  // ---- W21 = -W22 * T -> Tinv rows 64.., cols 0..63; W22 -> cols 64.. ----
  {
    const int tx = tid & 15, ty = tid >> 4;
    const int r0 = ty*2, c0 = tx*4;
    float acc[2][4];
    #pragma unroll
    for (int i=0;i<2;++i){acc[i][0]=0.f;acc[i][1]=0.f;acc[i][2]=0.f;acc[i][3]=0.f;}
    for (int k = 0; k < 64; ++k) {
      float a0 = R2[r0*66 + k], a1 = R2[(r0+1)*66 + k];
      float b0 = R[k*66 + c0],     b1 = R[k*66 + c0 + 1];
      float b2 = R[k*66 + c0 + 2], b3 = R[k*66 + c0 + 3];
      acc[0][0]+=a0*b0; acc[0][1]+=a0*b1; acc[0][2]+=a0*b2; acc[0][3]+=a0*b3;
      acc[1][0]+=a1*b0; acc[1][1]+=a1*b1; acc[1][2]+=a1*b2; acc[1][3]+=a1*b3;
    }
    #pragma unroll
    for (int i=0;i<2;++i)
      #pragma unroll
      for (int u=0;u<4;++u)
        Tinv[(size_t)(64 + r0 + i)*NB + c0 + u] = -acc[i][u];
  }
  for (int t = tid; t < 64*64; t += 512) {
    int i = t >> 6, c = t & 63;
    Tinv[(size_t)(64 + i)*NB + 64 + c] = R2[i*66 + c];
  }
}

// ============================================================================
// k_step: block0 = panel_duty(bpot); blocks>=1 = 2 syrk engines on trailing
// 64-tiles (minus the diag 128-block, presub'd). LDS ~51.7 KB -> 2 blocks/CU.
// ============================================================================
__global__ __launch_bounds__(512, 4)
void k_step(float* Abase, size_t aStride, int lda, int bpot, int presub, int doInv,
            float* TinvBase, size_t tStrideZ, size_t tStrideK,
            float* logsum, int slotBase, int limit,
            int R0, int q, int k0) {
  __shared__ __align__(16) float SM[12800];
  __shared__ float pivd[NB];
  const int z = blockIdx.z;
  float* A = Abase + (size_t)z*aStride;

  if (blockIdx.x == 0) {
    panel_duty(A, lda, bpot, presub, doInv,
               TinvBase + (size_t)z*tStrideZ + (size_t)bpot*tStrideK,
               logsum, slotBase + z*32 + bpot, limit, SM, pivd);
    return;
  }
  const int tid = threadIdx.x;
  int eng = tid >> 8, lt = tid & 255;
  int tileIdx = (blockIdx.x - 1)*2 + eng;
  int ntiles = q*(q+1)/2 - 3;
  int valid = (tileIdx < ntiles) ? 1 : 0;
  int idxp = valid ? tileIdx + 3 : 3;
  int r = (int)((sqrtf(8.f*(float)idxp + 1.f) - 1.f)*0.5f);
  while ((r+1)*(r+2)/2 <= idxp) ++r;
  while (r*(r+1)/2 > idxp) --r;
  int c = idxp - r*(r+1)/2;
  syrk64(A, lda, (R0+r)*64, (R0+c)*64, k0, valid,
         SM + eng*4352, SM + eng*4352 + 2176, lt);
}

// ---------------- trsm: L21 = A21 * Tinv^T (R3-proven) ----------------
__global__ __launch_bounds__(256)
void k_trsm(float* Abase, size_t aStride, int lda, int kblk,
            const float* TinvBase, size_t tStride) {
  __shared__ float As[32*68];
  __shared__ float Ts[32*132];
  const int tid = threadIdx.x;
  float* A = Abase + (size_t)blockIdx.z * aStride;
  const float* Tinv = TinvBase + (size_t)blockIdx.z * tStride;
  const int k0 = kblk * NB;
  const int row0 = k0 + NB + blockIdx.x * 64;
  const int tx = tid & 15, ty = tid >> 4;
  float acc[4][8];
  #pragma unroll
  for (int i = 0; i < 4; ++i)
    #pragma unroll
    for (int u = 0; u < 8; ++u) acc[i][u] = 0.f;
  for (int ks = 0; ks < NB; ks += 32) {
    for (int t = tid; t < 64*8; t += 256) {
      int r = t >> 3, q = t & 7;
      float4 v = *(const float4*)&A[(size_t)(row0 + r)*lda + k0 + ks + q*4];
      As[(q*4+0)*68 + r] = v.x; As[(q*4+1)*68 + r] = v.y;
      As[(q*4+2)*68 + r] = v.z; As[(q*4+3)*68 + r] = v.w;
    }
    for (int t = tid; t < 128*8; t += 256) {
      int c = t >> 3, q = t & 7;
      float4 v = *(const float4*)&Tinv[c*NB + ks + q*4];
      Ts[(q*4+0)*132 + c] = v.x; Ts[(q*4+1)*132 + c] = v.y;
      Ts[(q*4+2)*132 + c] = v.z; Ts[(q*4+3)*132 + c] = v.w;
    }
    __syncthreads();
    #pragma unroll
    for (int kk = 0; kk < 32; ++kk) {
      float a[4], b[8];
      *(float4*)a      = *(const float4*)&As[kk*68 + ty*4];
      *(float4*)&b[0]  = *(const float4*)&Ts[kk*132 + tx*8];
      *(float4*)&b[4]  = *(const float4*)&Ts[kk*132 + tx*8 + 4];
      #pragma unroll
      for (int i = 0; i < 4; ++i)
        #pragma unroll
        for (int u = 0; u < 8; ++u) acc[i][u] += a[i]*b[u];
    }
    __syncthreads();
  }
  #pragma unroll
  for (int i = 0; i < 4; ++i) {
    int r = row0 + ty*4 + i;
    *(float4*)&A[(size_t)r*lda + k0 + tx*8]     = make_float4(acc[i][0],acc[i][1],acc[i][2],acc[i][3]);
    *(float4*)&A[(size_t)r*lda + k0 + tx*8 + 4] = make_float4(acc[i][4],acc[i][5],acc[i][6],acc[i][7]);
  }
}

// ---------------- builders / solves / epilogue (proven, unchanged) ----------
__global__ __launch_bounds__(256)
void k_build_kb(const float* Xbar, const float* lsp, const float* stdp, const float* noisep,
                float* KbBase, size_t kbStride, int dimBase) {
  int z = blockIdx.z, d = dimBase + z;
  float* Kb = KbBase + (size_t)z*kbStride;
  int idx = blockIdx.x*256 + threadIdx.x;
  if (idx >= M_*M_) return;
  int i = idx >> 9, j = idx & 511;
  float ls = lsp[d], sd = stdp[d], nz = noisep[d];
  float df = Xbar[i*D_ + d] - Xbar[j*D_ + d];
  float v = sd*sd*expf(-0.5f*df*df/(ls*ls));
  if (i == j) v += nz*nz;
  Kb[idx] = v;
}

__global__ __launch_bounds__(256)
void k_build_kstar(const float* X, const float* Xbar, const float* lsp, const float* stdp,
                   float* KSBase, size_t ksStride, int dimBase) {
  int z = blockIdx.z, d = dimBase + z;
  float* KS = KSBase + (size_t)z*ksStride;
  int idx = blockIdx.x*256 + threadIdx.x;
  if (idx >= N_*M_) return;
  int i = idx >> 9, j = idx & 511;
  float ls = lsp[d], sd = stdp[d];
  float df = X[i*D_ + d] - Xbar[j*D_ + d];
  KS[idx] = sd*sd*expf(-0.5f*df*df/(ls*ls));
}

__global__ __launch_bounds__(256)
void k_csolve(float* CBase, size_t cStride, const float* KbBase, size_t kbStride,
              const float* TinvKbBase, size_t tkbStride, int J) {
  __shared__ float sm[12672];
  const int tid = threadIdx.x;
  float* C = CBase + (size_t)blockIdx.z*cStride;
  const float* L = KbBase + (size_t)blockIdx.z*kbStride;
  const float* Tinv = TinvKbBase + (size_t)blockIdx.z*tkbStride + (size_t)J*NB*NB;
  const int row0 = blockIdx.x*64;
  const int tx = tid & 15, ty = tid >> 4;
  float* As = sm; float* Ls = sm + 2176;
  float* Xs = sm; float* Ts = sm + 8448;
  float acc[4][8];
  #pragma unroll
  for (int i=0;i<4;++i) {
    const float* p = &C[(size_t)(row0+ty*4+i)*M_ + J*NB + tx*8];
    float4 v0 = *(const float4*)p, v1 = *(const float4*)(p+4);
    acc[i][0]=v0.x; acc[i][1]=v0.y; acc[i][2]=v0.z; acc[i][3]=v0.w;
    acc[i][4]=v1.x; acc[i][5]=v1.y; acc[i][6]=v1.z; acc[i][7]=v1.w;
  }
  for (int P = 0; P < J; ++P) {
    for (int ks = 0; ks < NB; ks += 32) {
      __syncthreads();
      for (int t = tid; t < 64*8; t += 256) {
        int r = t >> 3, q = t & 7;
        float4 v = *(const float4*)&C[(size_t)(row0+r)*M_ + P*NB + ks + q*4];
        As[(q*4+0)*68+r]=v.x; As[(q*4+1)*68+r]=v.y; As[(q*4+2)*68+r]=v.z; As[(q*4+3)*68+r]=v.w;
      }
      for (int t = tid; t < 128*8; t += 256) {
        int c = t >> 3, q = t & 7;
        float4 v = *(const float4*)&L[(size_t)(J*NB+c)*M_ + P*NB + ks + q*4];
        Ls[(q*4+0)*132+c]=v.x; Ls[(q*4+1)*132+c]=v.y; Ls[(q*4+2)*132+c]=v.z; Ls[(q*4+3)*132+c]=v.w;
      }
      __syncthreads();
      #pragma unroll
      for (int kk = 0; kk < 32; ++kk) {
        float a[4], b[8];
        *(float4*)a     = *(const float4*)&As[kk*68 + ty*4];
        *(float4*)&b[0] = *(const float4*)&Ls[kk*132 + tx*8];
        *(float4*)&b[4] = *(const float4*)&Ls[kk*132 + tx*8 + 4];
        #pragma unroll
        for (int i=0;i<4;++i)
          #pragma unroll
          for (int u=0;u<8;++u) acc[i][u] -= a[i]*b[u];
      }
    }
  }
  __syncthreads();
  #pragma unroll
  for (int i=0;i<4;++i)
    #pragma unroll
    for (int u=0;u<8;++u) Xs[(ty*4+i)*132 + tx*8+u] = acc[i][u];
  #pragma unroll
  for (int i=0;i<4;++i)
    #pragma unroll
    for (int u=0;u<8;++u) acc[i][u] = 0.f;
  for (int ms = 0; ms < NB; ms += 32) {
    for (int t = tid; t < 128*8; t += 256) {
      int c = t >> 3, q = t & 7;
      float4 v = *(const float4*)&Tinv[c*NB + ms + q*4];
      Ts[(q*4+0)*132+c]=v.x; Ts[(q*4+1)*132+c]=v.y; Ts[(q*4+2)*132+c]=v.z; Ts[(q*4+3)*132+c]=v.w;
    }
    __syncthreads();
    #pragma unroll
    for (int mm = 0; mm < 32; ++mm) {
      float a[4], b[8];
      a[0]=Xs[(ty*4+0)*132+ms+mm]; a[1]=Xs[(ty*4+1)*132+ms+mm];
      a[2]=Xs[(ty*4+2)*132+ms+mm]; a[3]=Xs[(ty*4+3)*132+ms+mm];
      *(float4*)&b[0] = *(const float4*)&Ts[mm*132 + tx*8];
      *(float4*)&b[4] = *(const float4*)&Ts[mm*132 + tx*8 + 4];
      #pragma unroll
      for (int i=0;i<4;++i)
        #pragma unroll
        for (int u=0;u<8;++u) acc[i][u] += a[i]*b[u];
    }
    __syncthreads();
  }
  #pragma unroll
  for (int i=0;i<4;++i) {
    float* p = &C[(size_t)(row0+ty*4+i)*M_ + J*NB + tx*8];
    *(float4*)p     = make_float4(acc[i][0],acc[i][1],acc[i][2],acc[i][3]);
    *(float4*)(p+4) = make_float4(acc[i][4],acc[i][5],acc[i][6],acc[i][7]);
  }
}

__global__ __launch_bounds__(256)
void k_fwdsub(const float* KbBase, size_t kbStride,
              const float* TkbBase, size_t tkbStride,
              const float* lls, float* wBase, size_t wStride, int dimBase) {
  __shared__ float w[M_];
  __shared__ float tv[NB];
  __shared__ float red[256];
  int z = blockIdx.z, d = dimBase + z;
  const float* L = KbBase + (size_t)z*kbStride;
  const float* Tk = TkbBase + (size_t)z*tkbStride;
  float* wout = wBase + (size_t)z*wStride;
  const int tid = threadIdx.x;
  for (int i = tid; i < M_; i += 256) w[i] = logf(fabsf(lls[i*D_ + d]));
  __syncthreads();
  const int r = tid >> 1, h = tid & 1;
  for (int J = 0; J < 4; ++J) {
    float s = 0.f;
    int half = (J*NB) >> 1;
    for (int k = h*half; k < (h+1)*half; k += 4) {
      float4 lv = *(const float4*)&L[(size_t)(J*NB + r)*M_ + k];
      s += lv.x*w[k] + lv.y*w[k+1] + lv.z*w[k+2] + lv.w*w[k+3];
    }
    red[tid] = s;
    __syncthreads();
    if (h == 0) tv[r] = w[J*NB + r] - red[2*r] - red[2*r+1];
    __syncthreads();
    const float* Ti = Tk + (size_t)J*NB*NB;
    s = 0.f;
    for (int k = h*64; k < h*64 + 64; k += 4) {
      float4 tw = *(const float4*)&Ti[r*NB + k];
      s += tw.x*tv[k] + tw.y*tv[k+1] + tw.z*tv[k+2] + tw.w*tv[k+3];
    }
    red[tid] = s;
    __syncthreads();
    if (h == 0) w[J*NB + r] = red[2*r] + red[2*r+1];
    __syncthreads();
  }
  for (int i = tid; i < M_; i += 256) wout[i] = w[i];
}

__global__ __launch_bounds__(256)
void k_gemv_l(const float* CBase, size_t cStride, const float* wBase, size_t wStride,
              float* lvec, int dimBase) {
  int z = blockIdx.z, d = dimBase + z;
  const float* C = CBase + (size_t)z*cStride;
  const float* w = wBase + (size_t)z*wStride;
  __shared__ float ws[M_];
  for (int i = threadIdx.x; i < M_; i += 256) ws[i] = w[i];
  __syncthreads();
  int wid = threadIdx.x >> 6, lane = threadIdx.x & 63;
  int row = blockIdx.x*4 + wid;
  if (row >= N_) return;
  float s = 0.f;
  const float* cr = &C[(size_t)row*M_];
  for (int k = lane; k < M_; k += 64) s += cr[k]*ws[k];
  for (int o = 32; o; o >>= 1) s += __shfl_down(s, o);
  if (lane == 0) lvec[row*D_ + d] = expf(s);
}

__global__ __launch_bounds__(256)
void k_kpost(const float* X, const float* lsp, const float* stdp,
             const float* CBase, size_t cStride,
             float* Abase, size_t aStride, int dimBase) {
  if (blockIdx.y > blockIdx.x) return;
  __shared__ float As[32*68];
  __shared__ float Bs[32*68];
  int z = blockIdx.z, d = dimBase + z;
  const float* C = CBase + (size_t)z*cStride;
  float* A = Abase + (size_t)z*aStride;
  const int row0 = blockIdx.x*64, col0 = blockIdx.y*64;
  const int tid = threadIdx.x, tx = tid & 15, ty = tid >> 4;
  float acc[4][4];
  #pragma unroll
  for (int i=0;i<4;++i) { acc[i][0]=0.f;acc[i][1]=0.f;acc[i][2]=0.f;acc[i][3]=0.f; }
  if (row0 < N_) {
    for (int ks = 0; ks < M_; ks += 32) {
      for (int t = tid; t < 64*8; t += 256) {
        int r = t >> 3, q = t & 7;
        float4 v = *(const float4*)&C[(size_t)(row0+r)*M_ + ks + q*4];
        As[(q*4+0)*68+r]=v.x; As[(q*4+1)*68+r]=v.y; As[(q*4+2)*68+r]=v.z; As[(q*4+3)*68+r]=v.w;
        float4 w2 = *(const float4*)&C[(size_t)(col0+r)*M_ + ks + q*4];
        Bs[(q*4+0)*68+r]=w2.x; Bs[(q*4+1)*68+r]=w2.y; Bs[(q*4+2)*68+r]=w2.z; Bs[(q*4+3)*68+r]=w2.w;
      }
      __syncthreads();
      #pragma unroll
      for (int kk=0; kk<32; ++kk) {
        float a[4], b[4];
        *(float4*)a = *(const float4*)&As[kk*68 + ty*4];
        *(float4*)b = *(const float4*)&Bs[kk*68 + tx*4];
        #pragma unroll
        for (int i=0;i<4;++i)
          #pragma unroll
          for (int u=0;u<4;++u) acc[i][u] += a[i]*b[u];
      }
      __syncthreads();
    }
  }
  float ls = lsp[d], sd = stdp[d];
  float inv2 = -0.5f/(ls*ls), s2 = sd*sd;
  #pragma unroll
  for (int i=0;i<4;++i) {
    int gi = row0 + ty*4 + i;
    float xi = (gi < N_) ? X[gi*D_ + d] : 0.f;
    #pragma unroll
    for (int u=0;u<4;++u) {
      int gj = col0 + tx*4 + u;
      float v;
      if (gi < N_ && gj < N_) {
        float df = xi - X[gj*D_ + d];
        v = s2*expf(inv2*df*df) - acc[i][u];
        if (gi == gj) v += JITTER_;
      } else {
        v = (gi == gj) ? 1.f : 0.f;
      }
      A[(size_t)gi*NPAD + gj] = v;
    }
  }
}

__global__ __launch_bounds__(256)
void k_kfinal(const float* X, const float* lvec, const float* y,
              const float* gstd, const float* gnoise, float* A) {
  int idx = blockIdx.x*256 + threadIdx.x;
  if (idx >= NPAD*NPAD) return;
  int gi = idx / NPAD, gj = idx - (idx/NPAD)*NPAD;
  float v;
  if (gi < N_ && gj < N_) {
    float gv = gstd[0]*gstd[0];
    float prod = 1.f, s = 0.f;
    #pragma unroll
    for (int d = 0; d < D_; ++d) {
      float l1 = lvec[gi*D_ + d], l2 = lvec[gj*D_ + d];
      float lsq = l1*l1 + l2*l2;
      prod *= 2.f*l1*l2/lsq;
      float df = X[gi*D_ + d] - X[gj*D_ + d];
      s += df*df/lsq;
    }
    v = gv * sqrtf(prod) * expf(-s);
    if (gi == gj) v += gnoise[0]*gnoise[0];
  } else if (gi == N_ && gj < N_) v = y[gj];
  else if (gj == N_ && gi < N_) v = y[gi];
  else if (gi == N_ && gj == N_) v = CBORD;
  else v = (gi == gj) ? 1.f : 0.f;
  A[idx] = v;
}

__global__ void k_finalize(const float* A, const float* logsum, float* out) {
  if (threadIdx.x != 0 || blockIdx.x != 0) return;
  float sumB = 0.f;
  for (int z = 0; z < 4; ++z)
    for (int k = 0; k < NBLK; ++k) {
      int slot = z*32 + k;
      sumB += logsum[slot*2] + logsum[slot*2+1];
    }
  float sumL = 0.f;
  for (int k = 0; k < NBLK; ++k) {
    int slot = 128 + k;
    sumL += logsum[slot*2] + logsum[slot*2+1];
  }
  float lb = A[(size_t)N_*NPAD + N_];
  float yKy = CBORD - lb*lb;
  const float LOG2PI = 1.8378770664093453f;
  float Aterm = 0.5f*(yKy + sumL + (float)N_*LOG2PI);
  float Bterm = sumB + 0.5f*(float)(M_*D_)*LOG2PI;
  out[0] = Aterm + Bterm;
}

// ============================================================================
// chain driver: {trsm; step} per k, potrf rides inside k_step block0.
// ============================================================================
static void run_chain(float* A, size_t aS, int lda, int nblk,
                      float* Tinv, size_t tz, size_t tk, int invAll,
                      float* lgs, int slotBase, int limit, int nz,
                      hipStream_t stream) {
  int doInv0 = (invAll || nblk > 1) ? 1 : 0;
  k_step<<<dim3(1,1,nz),512,0,stream>>>(A,aS,lda, 0,0,doInv0, Tinv,tz,tk,
                                        lgs,slotBase,limit, 0,0,0);
  for (int k = 0; k < nblk-1; ++k) {
    int m = nblk-1-k;
    k_trsm<<<dim3(2*m,1,nz),256,0,stream>>>(A,aS,lda,k, Tinv + (size_t)k*tk, tz);
    int q2 = 2*m, ntiles = q2*(q2+1)/2 - 3;
    int nbx = 1 + (ntiles+1)/2;
    int doInv = (invAll || (k+1 < nblk-1)) ? 1 : 0;
    k_step<<<dim3(nbx,1,nz),512,0,stream>>>(A,aS,lda, k+1,1,doInv, Tinv,tz,tk,
                                            lgs,slotBase,limit, (k+1)*2, q2, k*NB);
  }
}

extern "C" void kernel_launch(void* const* d_in, const int* in_sizes, int n_in,
                              void* d_out, int out_size, void* d_ws, size_t ws_size,
                              hipStream_t stream) {
  const float* X    = (const float*)d_in[0];
  const float* y    = (const float*)d_in[1];
  const float* Xbar = (const float*)d_in[2];
  const float* lgls = (const float*)d_in[3];
  const float* lgstd= (const float*)d_in[4];
  const float* lgnz = (const float*)d_in[5];
  const float* lls  = (const float*)d_in[6];
  const float* gstd = (const float*)d_in[7];
  const float* gnz  = (const float*)d_in[8];
  float* out = (float*)d_out;

  const size_t A_SZ   = (size_t)NPAD*NPAD;
  const size_t KS_SZ  = (size_t)N_*M_;
  const size_t KB_SZ  = (size_t)M_*M_;
  const size_t TKB_SZ = (size_t)4*NB*NB;
  const size_t TBG_SZ = (size_t)NB*NB;
  const size_t W_SZ   = (size_t)M_;
  const size_t LV_SZ  = (size_t)N_*D_;
  const size_t LOG_SZ = 1024;

  size_t need2 = (5*A_SZ + 4*(KS_SZ + KB_SZ + TKB_SZ + W_SZ) + 5*TBG_SZ
                  + LV_SZ + LOG_SZ + 1024);
  size_t per1  = A_SZ + KS_SZ + KB_SZ + TKB_SZ + TBG_SZ + W_SZ;
  size_t need1 = 4*per1 + LV_SZ + LOG_SZ + 256;

  if (ws_size >= need2 * sizeof(float)) {
    // ---------- merged mode: one 25-step lookahead chain over 5 matrices ----
    float* p = (float*)d_ws;
    float* A    = p; p += 5*A_SZ;
    float* KS   = p; p += 4*KS_SZ;
    float* Kb   = p; p += 4*KB_SZ;
    float* Tkb  = p; p += 4*TKB_SZ;
    float* Tbig = p; p += 5*TBG_SZ;
    float* wv   = p; p += 4*W_SZ;
    float* lv   = p; p += LV_SZ;
    float* lgs  = p; p += LOG_SZ;

    k_build_kb<<<dim3((M_*M_+255)/256,1,4),256,0,stream>>>(Xbar,lgls,lgstd,lgnz,Kb,KB_SZ,0);
    run_chain(Kb, KB_SZ, M_, MBLK, Tkb, TKB_SZ, (size_t)NB*NB, 1, lgs, 192, 0, 4, stream);
    k_fwdsub<<<dim3(1,1,4),256,0,stream>>>(Kb,KB_SZ,Tkb,TKB_SZ,lls,wv,W_SZ,0);
    k_build_kstar<<<dim3((N_*M_+255)/256,1,4),256,0,stream>>>(X,Xbar,lgls,lgstd,KS,KS_SZ,0);
    for (int J = 0; J < MBLK; ++J)
      k_csolve<<<dim3(N_/64,1,4),256,0,stream>>>(KS,KS_SZ,Kb,KB_SZ,Tkb,TKB_SZ,J);
    k_gemv_l<<<dim3(N_/4,1,4),256,0,stream>>>(KS,KS_SZ,wv,W_SZ,lv,0);
    k_kpost<<<dim3(NPAD/64,NPAD/64,4),256,0,stream>>>(X,lgls,lgstd,KS,KS_SZ,A,A_SZ,0);
    k_kfinal<<<dim3((NPAD*NPAD+255)/256,1,1),256,0,stream>>>(X,lv,y,gstd,gnz,A+4*A_SZ);
    run_chain(A, A_SZ, NPAD, NBLK, Tbig, TBG_SZ, 0, 0, lgs, 0, N_, 5, stream);
    k_finalize<<<1,64,0,stream>>>(A+4*A_SZ,lgs,out);
    return;
  }

  // ---------- small-ws fallback: sequential passes ----------
  bool batched = ws_size >= need1 * sizeof(float);
  int nz = batched ? 4 : 1;
  float* p = (float*)d_ws;
  float* A    = p; p += (size_t)nz*A_SZ;
  float* KS   = p; p += (size_t)nz*KS_SZ;
  float* Kb   = p; p += (size_t)nz*KB_SZ;
  float* Tkb  = p; p += (size_t)nz*TKB_SZ;
  float* Tbig = p; p += (size_t)nz*TBG_SZ;
  float* wv   = p; p += (size_t)nz*W_SZ;
  float* lv   = p; p += LV_SZ;
  float* lgs  = p; p += LOG_SZ;

  int npass = batched ? 1 : 4;
  for (int pass = 0; pass < npass; ++pass) {
    int dimBase  = batched ? 0 : pass;
    int slotBase = batched ? 0 : pass*32;
    k_build_kb<<<dim3((M_*M_+255)/256,1,nz),256,0,stream>>>(Xbar,lgls,lgstd,lgnz,Kb,KB_SZ,dimBase);
    run_chain(Kb, KB_SZ, M_, MBLK, Tkb, TKB_SZ, (size_t)NB*NB, 1, lgs, 192+slotBase, 0, nz, stream);
    k_fwdsub<<<dim3(1,1,nz),256,0,stream>>>(Kb,KB_SZ,Tkb,TKB_SZ,lls,wv,W_SZ,dimBase);
    k_build_kstar<<<dim3((N_*M_+255)/256,1,nz),256,0,stream>>>(X,Xbar,lgls,lgstd,KS,KS_SZ,dimBase);
    for (int J = 0; J < MBLK; ++J)
      k_csolve<<<dim3(N_/64,1,nz),256,0,stream>>>(KS,KS_SZ,Kb,KB_SZ,Tkb,TKB_SZ,J);
    k_gemv_l<<<dim3(N_/4,1,nz),256,0,stream>>>(KS,KS_SZ,wv,W_SZ,lv,dimBase);
    k_kpost<<<dim3(NPAD/64,NPAD/64,nz),256,0,stream>>>(X,lgls,lgstd,KS,KS_SZ,A,A_SZ,dimBase);
    run_chain(A, A_SZ, NPAD, NBLK, Tbig, TBG_SZ, 0, 0, lgs, slotBase, N_, nz, stream);
  }
  k_kfinal<<<dim3((NPAD*NPAD+255)/256,1,1),256,0,stream>>>(X,lv,y,gstd,gnz,A);
  run_chain(A, A_SZ, NPAD, NBLK, Tbig, TBG_SZ, 0, 0, lgs, 128, N_, 1, stream);
  k_finalize<<<1,64,0,stream>>>(A,lgs,out);
}

// Round 11
// 14407.039 us; speedup vs baseline: 1.0271x; 1.0271x over previous
//
#include <hip/hip_runtime.h>
#include <math.h>

#define N_   3072
#define D_   4
#define M_   512
#define NPAD 3200
#define NB   128
#define NBLK (NPAD/NB)   // 25
#define MBLK (M_/NB)     // 4
#define JITTER_ 0.05f
#define CBORD 32768.0f

// ============================================================================
// syrk64 engine: A[gr0..+64, gc0..+64] -= P_r P_c^T over cols [k0,k0+128).
// 256 threads. As/Bs = 2176 floats each (R3/R5-proven).
// ============================================================================
__device__ void syrk64(float* A, int lda, int gr0, int gc0, int k0,
                       float* As, float* Bs, int lt) {
  const int tx = lt & 15, ty = lt >> 4;
  float acc[4][4];
  #pragma unroll
  for (int i=0;i<4;++i){acc[i][0]=0.f;acc[i][1]=0.f;acc[i][2]=0.f;acc[i][3]=0.f;}
  for (int ks = 0; ks < NB; ks += 32) {
    __syncthreads();
    for (int t = lt; t < 64*8; t += 256) {
      int rr = t >> 3, qq = t & 7;
      float4 v = *(const float4*)&A[(size_t)(gr0+rr)*lda + k0 + ks + qq*4];
      As[(qq*4+0)*68+rr]=v.x; As[(qq*4+1)*68+rr]=v.y;
      As[(qq*4+2)*68+rr]=v.z; As[(qq*4+3)*68+rr]=v.w;
      float4 w = *(const float4*)&A[(size_t)(gc0+rr)*lda + k0 + ks + qq*4];
      Bs[(qq*4+0)*68+rr]=w.x; Bs[(qq*4+1)*68+rr]=w.y;
      Bs[(qq*4+2)*68+rr]=w.z; Bs[(qq*4+3)*68+rr]=w.w;
    }
    __syncthreads();
    #pragma unroll
    for (int kk = 0; kk < 32; ++kk) {
      float a[4], b[4];
      *(float4*)a = *(const float4*)&As[kk*68 + ty*4];
      *(float4*)b = *(const float4*)&Bs[kk*68 + tx*4];
      #pragma unroll
      for (int i=0;i<4;++i)
        #pragma unroll
        for (int u=0;u<4;++u) acc[i][u] += a[i]*b[u];
    }
  }
  #pragma unroll
  for (int i=0;i<4;++i) {
    size_t off = (size_t)(gr0 + ty*4 + i)*lda + gc0 + tx*4;
    float4 v = *(const float4*)&A[off];
    v.x -= acc[i][0]; v.y -= acc[i][1]; v.z -= acc[i][2]; v.w -= acc[i][3];
    *(float4*)&A[off] = v;
  }
}

// ============================================================================
// panel_duty: 256 threads, LDS = B1(4352)+B2(4352)+pivd(128).
//  1) presub: diag block -= panel_k panel_k^T (3 syrk64 tiles, global RMW)
//  2) left-looking factor: 4 sub-panels of 32 cols (row-major stride-33 LDS,
//     staged presub GEMMs from stored L, raw-pivot 32-step factor, scale+store)
//  3) inverse: 4 parallel 32x32 diag inverses (64-thr groups) + 6 off-diag
//     blocks via small GEMMs (L/W from global, same-block L1-safe) -> Tinv.
// ============================================================================
__device__ void panel_duty(float* A, int lda, int bpot, int presub, int doInv,
                           float* Tinv, float* logsum, int slot, int limit,
                           float* B1, float* B2, float* pivd) {
  const int tid = threadIdx.x;
  const int dj = bpot * NB;
  if (presub) {
    const int k0 = dj - NB;
    syrk64(A, lda, dj,    dj,    k0, B1, B1+2176, tid);
    __syncthreads();
    syrk64(A, lda, dj+64, dj,    k0, B1, B1+2176, tid);
    __syncthreads();
    syrk64(A, lda, dj+64, dj+64, k0, B1, B1+2176, tid);
    __syncthreads();
  }
  float* P = B1;   // [128][33] row-major
  float* S = B2;   // [128][33] row-major
  for (int sp = 0; sp < 4; ++sp) {
    const int c0 = sp*32;
    // load P (coalesced rows)
    for (int t = tid; t < 128*32; t += 256) {
      int r = t >> 5, c = t & 31;
      int gc = c0 + c;
      P[r*33 + c] = (r >= gc) ? A[(size_t)(dj+r)*lda + dj + gc] : 0.f;
    }
    __syncthreads();
    // presub from prior sub-panels
    for (int p = 0; p < sp; ++p) {
      for (int t = tid; t < 128*32; t += 256) {
        int r = t >> 5, c = t & 31;
        int gc = p*32 + c;
        S[r*33 + c] = (r >= gc) ? A[(size_t)(dj+r)*lda + dj + gc] : 0.f;
      }
      __syncthreads();
      for (int t = tid; t < 128*32; t += 256) {
        int r = t >> 5, c = t & 31;
        if (r >= c0 + c) {
          float s = 0.f;
          #pragma unroll
          for (int j = 0; j < 32; ++j)
            s += S[r*33 + j] * S[(c0+c)*33 + j];
          P[r*33 + c] -= s;
        }
      }
      __syncthreads();
    }
    // raw-pivot factor of 32 cols (1 barrier/step, deferred scaling)
    for (int j = 0; j < 32; ++j) {
      int gj = c0 + j;
      float d = fmaxf(P[gj*33 + j], 1e-30f);
      if (tid == 0) pivd[gj] = d;
      float rd = 1.0f / d;
      int wn = 31 - j;
      for (int t = tid; t < wn*128; t += 256) {
        int c = j + 1 + t / 128, r = t & 127;
        if (r >= c0 + c)
          P[r*33 + c] -= P[r*33 + j] * P[(c0+c)*33 + j] * rd;
      }
      __syncthreads();
    }
    // scale + store
    for (int t = tid; t < 128*32; t += 256) {
      int r = t >> 5, c = t & 31;
      int gc = c0 + c;
      if (r >= gc) {
        float dd = pivd[gc];
        float v = P[r*33 + c];
        v = (r == gc) ? sqrtf(dd) : v * rsqrtf(dd);
        A[(size_t)(dj+r)*lda + dj + gc] = v;
      }
    }
    __syncthreads();
  }
  // logsum (0.5*log raw pivots)
  {
    float lg = 0.f;
    if (tid < NB) {
      int g = dj + tid;
      if (g < limit) lg = 0.5f * logf(pivd[tid]);
    }
    for (int o = 32; o; o >>= 1) lg += __shfl_down(lg, o);
    int wv = tid >> 6;
    if ((tid & 63) == 0 && wv < 2) logsum[slot*2 + wv] = lg;
  }
  if (!doInv) return;
  // ---- inverse ----
  // load 4 diag 32x32 L blocks into B1
  for (int t = tid; t < 4*1024; t += 256) {
    int g = t >> 10, e = t & 1023, r = e >> 5, c = e & 31;
    B1[g*1056 + r*33 + c] = (r >= c) ? A[(size_t)(dj+g*32+r)*lda + dj + g*32 + c] : 0.f;
  }
  __syncthreads();
  {
    int g = tid >> 6, lane = tid & 63;
    float* Lg = B1 + g*1056;
    float* Rg = B2 + g*1056;
    for (int t = lane; t < 1024; t += 64) {
      int r = t >> 5, c = t & 31;
      Rg[r*33 + c] = (r == c) ? 1.f : 0.f;
    }
    __syncthreads();
    for (int j = 0; j < 32; ++j) {
      float dinv = 1.0f / Lg[j*33 + j];
      for (int t = lane; t < 1024; t += 64) {
        int i = t >> 5, c = t & 31;
        if (i > j && c <= j)
          Rg[i*33 + c] -= Lg[i*33 + j] * Rg[j*33 + c] * dinv;
      }
      __syncthreads();
    }
    for (int t = lane; t < 1024; t += 64) {
      int i = t >> 5, c = t & 31;
      if (c <= i) Rg[i*33 + c] *= 1.0f / Lg[i*33 + i];
    }
    __syncthreads();
  }
  // write diag W blocks + zeros
  for (int t = tid; t < NB*NB; t += 256) {
    int r = t >> 7, c = t & 127;
    int I = r >> 5, J = c >> 5;
    float v = 0.f;
    if (I == J) v = B2[I*1056 + (r&31)*33 + (c&31)];
    Tinv[r*NB + c] = v;
  }
  __syncthreads();
  // off-diag blocks by distance (L and W from global; W[I][I] in B2)
  for (int d = 1; d < 4; ++d) {
    for (int J = 0; J + d < 4; ++J) {
      int I = J + d;
      for (int t = tid; t < 1024; t += 256) {
        int r = t >> 5, c = t & 31;
        float s = 0.f;
        for (int K = J; K < I; ++K) {
          const float* Arow = &A[(size_t)(dj+I*32+r)*lda + dj + K*32];
          const float* Wcol = &Tinv[(size_t)(K*32)*NB + J*32 + c];
          #pragma unroll
          for (int k2 = 0; k2 < 32; ++k2)
            s += Arow[k2] * Wcol[(size_t)k2*NB];
        }
        B1[r*33 + c] = s;
      }
      __syncthreads();
      for (int t = tid; t < 1024; t += 256) {
        int r = t >> 5, c = t & 31;
        float s = 0.f;
        #pragma unroll
        for (int k2 = 0; k2 < 32; ++k2)
          s += B2[I*1056 + r*33 + k2] * B1[k2*33 + c];
        Tinv[(size_t)(I*32+r)*NB + J*32 + c] = -s;
      }
      __syncthreads();
    }
  }
}

// ============================================================================
// k_step: block0 = panel_duty(bpot); blocks>=1 = one syrk64 tile each.
// Static LDS ~35 KB -> 4 blocks/CU (4 independent barrier domains).
// ============================================================================
__global__ __launch_bounds__(256)
void k_step(float* Abase, size_t aStride, int lda, int bpot, int presub, int doInv,
            float* TinvBase, size_t tStrideZ, size_t tStrideK,
            float* logsum, int slotBase, int limit,
            int R0, int q, int k0) {
  __shared__ __align__(16) float B1[4352];
  __shared__ __align__(16) float B2[4352];
  __shared__ float pivd[NB];
  const int z = blockIdx.z;
  float* A = Abase + (size_t)z*aStride;

  if (blockIdx.x == 0) {
    panel_duty(A, lda, bpot, presub, doInv,
               TinvBase + (size_t)z*tStrideZ + (size_t)bpot*tStrideK,
               logsum, slotBase + z*32 + bpot, limit, B1, B2, pivd);
    return;
  }
  const int tid = threadIdx.x;
  int tileIdx = blockIdx.x - 1;
  int idxp = tileIdx + 3;          // skip the 3 diag-block tiles (presub'd)
  int r = (int)((sqrtf(8.f*(float)idxp + 1.f) - 1.f)*0.5f);
  while ((r+1)*(r+2)/2 <= idxp) ++r;
  while (r*(r+1)/2 > idxp) --r;
  int c = idxp - r*(r+1)/2;
  syrk64(A, lda, (R0+r)*64, (R0+c)*64, k0, B1, B1+2176, tid);
}

// k_init: panel only (no presub).
__global__ __launch_bounds__(256)
void k_init(float* Abase, size_t aStride, int lda, float* TinvBase, size_t tz,
            float* logsum, int slotBase, int limit, int doInv) {
  __shared__ __align__(16) float B1[4352];
  __shared__ __align__(16) float B2[4352];
  __shared__ float pivd[NB];
  int z = blockIdx.z;
  panel_duty(Abase + (size_t)z*aStride, lda, 0, 0, doInv,
             TinvBase + (size_t)z*tz, logsum, slotBase + z*32, limit, B1, B2, pivd);
}

// ---------------- trsm: L21 = A21 * Tinv^T (R3-proven) ----------------
__global__ __launch_bounds__(256)
void k_trsm(float* Abase, size_t aStride, int lda, int kblk,
            const float* TinvBase, size_t tStride) {
  __shared__ float As[32*68];
  __shared__ float Ts[32*132];
  const int tid = threadIdx.x;
  float* A = Abase + (size_t)blockIdx.z * aStride;
  const float* Tinv = TinvBase + (size_t)blockIdx.z * tStride;
  const int k0 = kblk * NB;
  const int row0 = k0 + NB + blockIdx.x * 64;
  const int tx = tid & 15, ty = tid >> 4;
  float acc[4][8];
  #pragma unroll
  for (int i = 0; i < 4; ++i)
    #pragma unroll
    for (int u = 0; u < 8; ++u) acc[i][u] = 0.f;
  for (int ks = 0; ks < NB; ks += 32) {
    for (int t = tid; t < 64*8; t += 256) {
      int r = t >> 3, q = t & 7;
      float4 v = *(const float4*)&A[(size_t)(row0 + r)*lda + k0 + ks + q*4];
      As[(q*4+0)*68 + r] = v.x; As[(q*4+1)*68 + r] = v.y;
      As[(q*4+2)*68 + r] = v.z; As[(q*4+3)*68 + r] = v.w;
    }
    for (int t = tid; t < 128*8; t += 256) {
      int c = t >> 3, q = t & 7;
      float4 v = *(const float4*)&Tinv[c*NB + ks + q*4];
      Ts[(q*4+0)*132 + c] = v.x; Ts[(q*4+1)*132 + c] = v.y;
      Ts[(q*4+2)*132 + c] = v.z; Ts[(q*4+3)*132 + c] = v.w;
    }
    __syncthreads();
    #pragma unroll
    for (int kk = 0; kk < 32; ++kk) {
      float a[4], b[8];
      *(float4*)a      = *(const float4*)&As[kk*68 + ty*4];
      *(float4*)&b[0]  = *(const float4*)&Ts[kk*132 + tx*8];
      *(float4*)&b[4]  = *(const float4*)&Ts[kk*132 + tx*8 + 4];
      #pragma unroll
      for (int i = 0; i < 4; ++i)
        #pragma unroll
        for (int u = 0; u < 8; ++u) acc[i][u] += a[i]*b[u];
    }
    __syncthreads();
  }
  #pragma unroll
  for (int i = 0; i < 4; ++i) {
    int r = row0 + ty*4 + i;
    *(float4*)&A[(size_t)r*lda + k0 + tx*8]     = make_float4(acc[i][0],acc[i][1],acc[i][2],acc[i][3]);
    *(float4*)&A[(size_t)r*lda + k0 + tx*8 + 4] = make_float4(acc[i][4],acc[i][5],acc[i][6],acc[i][7]);
  }
}

// ---------------- builders / solves / epilogue (proven, unchanged) ----------
__global__ __launch_bounds__(256)
void k_build_kb(const float* Xbar, const float* lsp, const float* stdp, const float* noisep,
                float* KbBase, size_t kbStride, int dimBase) {
  int z = blockIdx.z, d = dimBase + z;
  float* Kb = KbBase + (size_t)z*kbStride;
  int idx = blockIdx.x*256 + threadIdx.x;
  if (idx >= M_*M_) return;
  int i = idx >> 9, j = idx & 511;
  float ls = lsp[d], sd = stdp[d], nz = noisep[d];
  float df = Xbar[i*D_ + d] - Xbar[j*D_ + d];
  float v = sd*sd*expf(-0.5f*df*df/(ls*ls));
  if (i == j) v += nz*nz;
  Kb[idx] = v;
}

__global__ __launch_bounds__(256)
void k_build_kstar(const float* X, const float* Xbar, const float* lsp, const float* stdp,
                   float* KSBase, size_t ksStride, int dimBase) {
  int z = blockIdx.z, d = dimBase + z;
  float* KS = KSBase + (size_t)z*ksStride;
  int idx = blockIdx.x*256 + threadIdx.x;
  if (idx >= N_*M_) return;
  int i = idx >> 9, j = idx & 511;
  float ls = lsp[d], sd = stdp[d];
  float df = X[i*D_ + d] - Xbar[j*D_ + d];
  KS[idx] = sd*sd*expf(-0.5f*df*df/(ls*ls));
}

__global__ __launch_bounds__(256)
void k_csolve(float* CBase, size_t cStride, const float* KbBase, size_t kbStride,
              const float* TinvKbBase, size_t tkbStride, int J) {
  __shared__ float sm[12672];
  const int tid = threadIdx.x;
  float* C = CBase + (size_t)blockIdx.z*cStride;
  const float* L = KbBase + (size_t)blockIdx.z*kbStride;
  const float* Tinv = TinvKbBase + (size_t)blockIdx.z*tkbStride + (size_t)J*NB*NB;
  const int row0 = blockIdx.x*64;
  const int tx = tid & 15, ty = tid >> 4;
  float* As = sm; float* Ls = sm + 2176;
  float* Xs = sm; float* Ts = sm + 8448;
  float acc[4][8];
  #pragma unroll
  for (int i=0;i<4;++i) {
    const float* p = &C[(size_t)(row0+ty*4+i)*M_ + J*NB + tx*8];
    float4 v0 = *(const float4*)p, v1 = *(const float4*)(p+4);
    acc[i][0]=v0.x; acc[i][1]=v0.y; acc[i][2]=v0.z; acc[i][3]=v0.w;
    acc[i][4]=v1.x; acc[i][5]=v1.y; acc[i][6]=v1.z; acc[i][7]=v1.w;
  }
  for (int P = 0; P < J; ++P) {
    for (int ks = 0; ks < NB; ks += 32) {
      __syncthreads();
      for (int t = tid; t < 64*8; t += 256) {
        int r = t >> 3, q = t & 7;
        float4 v = *(const float4*)&C[(size_t)(row0+r)*M_ + P*NB + ks + q*4];
        As[(q*4+0)*68+r]=v.x; As[(q*4+1)*68+r]=v.y; As[(q*4+2)*68+r]=v.z; As[(q*4+3)*68+r]=v.w;
      }
      for (int t = tid; t < 128*8; t += 256) {
        int c = t >> 3, q = t & 7;
        float4 v = *(const float4*)&L[(size_t)(J*NB+c)*M_ + P*NB + ks + q*4];
        Ls[(q*4+0)*132+c]=v.x; Ls[(q*4+1)*132+c]=v.y; Ls[(q*4+2)*132+c]=v.z; Ls[(q*4+3)*132+c]=v.w;
      }
      __syncthreads();
      #pragma unroll
      for (int kk = 0; kk < 32; ++kk) {
        float a[4], b[8];
        *(float4*)a     = *(const float4*)&As[kk*68 + ty*4];
        *(float4*)&b[0] = *(const float4*)&Ls[kk*132 + tx*8];
        *(float4*)&b[4] = *(const float4*)&Ls[kk*132 + tx*8 + 4];
        #pragma unroll
        for (int i=0;i<4;++i)
          #pragma unroll
          for (int u=0;u<8;++u) acc[i][u] -= a[i]*b[u];
      }
    }
  }
  __syncthreads();
  #pragma unroll
  for (int i=0;i<4;++i)
    #pragma unroll
    for (int u=0;u<8;++u) Xs[(ty*4+i)*132 + tx*8+u] = acc[i][u];
  #pragma unroll
  for (int i=0;i<4;++i)
    #pragma unroll
    for (int u=0;u<8;++u) acc[i][u] = 0.f;
  for (int ms = 0; ms < NB; ms += 32) {
    for (int t = tid; t < 128*8; t += 256) {
      int c = t >> 3, q = t & 7;
      float4 v = *(const float4*)&Tinv[c*NB + ms + q*4];
      Ts[(q*4+0)*132+c]=v.x; Ts[(q*4+1)*132+c]=v.y; Ts[(q*4+2)*132+c]=v.z; Ts[(q*4+3)*132+c]=v.w;
    }
    __syncthreads();
    #pragma unroll
    for (int mm = 0; mm < 32; ++mm) {
      float a[4], b[8];
      a[0]=Xs[(ty*4+0)*132+ms+mm]; a[1]=Xs[(ty*4+1)*132+ms+mm];
      a[2]=Xs[(ty*4+2)*132+ms+mm]; a[3]=Xs[(ty*4+3)*132+ms+mm];
      *(float4*)&b[0] = *(const float4*)&Ts[mm*132 + tx*8];
      *(float4*)&b[4] = *(const float4*)&Ts[mm*132 + tx*8 + 4];
      #pragma unroll
      for (int i=0;i<4;++i)
        #pragma unroll
        for (int u=0;u<8;++u) acc[i][u] += a[i]*b[u];
    }
    __syncthreads();
  }
  #pragma unroll
  for (int i=0;i<4;++i) {
    float* p = &C[(size_t)(row0+ty*4+i)*M_ + J*NB + tx*8];
    *(float4*)p     = make_float4(acc[i][0],acc[i][1],acc[i][2],acc[i][3]);
    *(float4*)(p+4) = make_float4(acc[i][4],acc[i][5],acc[i][6],acc[i][7]);
  }
}

__global__ __launch_bounds__(256)
void k_fwdsub(const float* KbBase, size_t kbStride,
              const float* TkbBase, size_t tkbStride,
              const float* lls, float* wBase, size_t wStride, int dimBase) {
  __shared__ float w[M_];
  __shared__ float tv[NB];
  __shared__ float red[256];
  int z = blockIdx.z, d = dimBase + z;
  const float* L = KbBase + (size_t)z*kbStride;
  const float* Tk = TkbBase + (size_t)z*tkbStride;
  float* wout = wBase + (size_t)z*wStride;
  const int tid = threadIdx.x;
  for (int i = tid; i < M_; i += 256) w[i] = logf(fabsf(lls[i*D_ + d]));
  __syncthreads();
  const int r = tid >> 1, h = tid & 1;
  for (int J = 0; J < 4; ++J) {
    float s = 0.f;
    int half = (J*NB) >> 1;
    for (int k = h*half; k < (h+1)*half; k += 4) {
      float4 lv = *(const float4*)&L[(size_t)(J*NB + r)*M_ + k];
      s += lv.x*w[k] + lv.y*w[k+1] + lv.z*w[k+2] + lv.w*w[k+3];
    }
    red[tid] = s;
    __syncthreads();
    if (h == 0) tv[r] = w[J*NB + r] - red[2*r] - red[2*r+1];
    __syncthreads();
    const float* Ti = Tk + (size_t)J*NB*NB;
    s = 0.f;
    for (int k = h*64; k < h*64 + 64; k += 4) {
      float4 tw = *(const float4*)&Ti[r*NB + k];
      s += tw.x*tv[k] + tw.y*tv[k+1] + tw.z*tv[k+2] + tw.w*tv[k+3];
    }
    red[tid] = s;
    __syncthreads();
    if (h == 0) w[J*NB + r] = red[2*r] + red[2*r+1];
    __syncthreads();
  }
  for (int i = tid; i < M_; i += 256) wout[i] = w[i];
}

__global__ __launch_bounds__(256)
void k_gemv_l(const float* CBase, size_t cStride, const float* wBase, size_t wStride,
              float* lvec, int dimBase) {
  int z = blockIdx.z, d = dimBase + z;
  const float* C = CBase + (size_t)z*cStride;
  const float* w = wBase + (size_t)z*wStride;
  __shared__ float ws[M_];
  for (int i = threadIdx.x; i < M_; i += 256) ws[i] = w[i];
  __syncthreads();
  int wid = threadIdx.x >> 6, lane = threadIdx.x & 63;
  int row = blockIdx.x*4 + wid;
  if (row >= N_) return;
  float s = 0.f;
  const float* cr = &C[(size_t)row*M_];
  for (int k = lane; k < M_; k += 64) s += cr[k]*ws[k];
  for (int o = 32; o; o >>= 1) s += __shfl_down(s, o);
  if (lane == 0) lvec[row*D_ + d] = expf(s);
}

__global__ __launch_bounds__(256)
void k_kpost(const float* X, const float* lsp, const float* stdp,
             const float* CBase, size_t cStride,
             float* Abase, size_t aStride, int dimBase) {
  if (blockIdx.y > blockIdx.x) return;
  __shared__ float As[32*68];
  __shared__ float Bs[32*68];
  int z = blockIdx.z, d = dimBase + z;
  const float* C = CBase + (size_t)z*cStride;
  float* A = Abase + (size_t)z*aStride;
  const int row0 = blockIdx.x*64, col0 = blockIdx.y*64;
  const int tid = threadIdx.x, tx = tid & 15, ty = tid >> 4;
  float acc[4][4];
  #pragma unroll
  for (int i=0;i<4;++i) { acc[i][0]=0.f;acc[i][1]=0.f;acc[i][2]=0.f;acc[i][3]=0.f; }
  if (row0 < N_) {
    for (int ks = 0; ks < M_; ks += 32) {
      for (int t = tid; t < 64*8; t += 256) {
        int r = t >> 3, q = t & 7;
        float4 v = *(const float4*)&C[(size_t)(row0+r)*M_ + ks + q*4];
        As[(q*4+0)*68+r]=v.x; As[(q*4+1)*68+r]=v.y; As[(q*4+2)*68+r]=v.z; As[(q*4+3)*68+r]=v.w;
        float4 w2 = *(const float4*)&C[(size_t)(col0+r)*M_ + ks + q*4];
        Bs[(q*4+0)*68+r]=w2.x; Bs[(q*4+1)*68+r]=w2.y; Bs[(q*4+2)*68+r]=w2.z; Bs[(q*4+3)*68+r]=w2.w;
      }
      __syncthreads();
      #pragma unroll
      for (int kk=0; kk<32; ++kk) {
        float a[4], b[4];
        *(float4*)a = *(const float4*)&As[kk*68 + ty*4];
        *(float4*)b = *(const float4*)&Bs[kk*68 + tx*4];
        #pragma unroll
        for (int i=0;i<4;++i)
          #pragma unroll
          for (int u=0;u<4;++u) acc[i][u] += a[i]*b[u];
      }
      __syncthreads();
    }
  }
  float ls = lsp[d], sd = stdp[d];
  float inv2 = -0.5f/(ls*ls), s2 = sd*sd;
  #pragma unroll
  for (int i=0;i<4;++i) {
    int gi = row0 + ty*4 + i;
    float xi = (gi < N_) ? X[gi*D_ + d] : 0.f;
    #pragma unroll
    for (int u=0;u<4;++u) {
      int gj = col0 + tx*4 + u;
      float v;
      if (gi < N_ && gj < N_) {
        float df = xi - X[gj*D_ + d];
        v = s2*expf(inv2*df*df) - acc[i][u];
        if (gi == gj) v += JITTER_;
      } else {
        v = (gi == gj) ? 1.f : 0.f;
      }
      A[(size_t)gi*NPAD + gj] = v;
    }
  }
}

__global__ __launch_bounds__(256)
void k_kfinal(const float* X, const float* lvec, const float* y,
              const float* gstd, const float* gnoise, float* A) {
  int idx = blockIdx.x*256 + threadIdx.x;
  if (idx >= NPAD*NPAD) return;
  int gi = idx / NPAD, gj = idx - (idx/NPAD)*NPAD;
  float v;
  if (gi < N_ && gj < N_) {
    float gv = gstd[0]*gstd[0];
    float prod = 1.f, s = 0.f;
    #pragma unroll
    for (int d = 0; d < D_; ++d) {
      float l1 = lvec[gi*D_ + d], l2 = lvec[gj*D_ + d];
      float lsq = l1*l1 + l2*l2;
      prod *= 2.f*l1*l2/lsq;
      float df = X[gi*D_ + d] - X[gj*D_ + d];
      s += df*df/lsq;
    }
    v = gv * sqrtf(prod) * expf(-s);
    if (gi == gj) v += gnoise[0]*gnoise[0];
  } else if (gi == N_ && gj < N_) v = y[gj];
  else if (gj == N_ && gi < N_) v = y[gi];
  else if (gi == N_ && gj == N_) v = CBORD;
  else v = (gi == gj) ? 1.f : 0.f;
  A[idx] = v;
}

__global__ void k_finalize(const float* A, const float* logsum, float* out) {
  if (threadIdx.x != 0 || blockIdx.x != 0) return;
  float sumB = 0.f;
  for (int z = 0; z < 4; ++z)
    for (int k = 0; k < NBLK; ++k) {
      int slot = z*32 + k;
      sumB += logsum[slot*2] + logsum[slot*2+1];
    }
  float sumL = 0.f;
  for (int k = 0; k < NBLK; ++k) {
    int slot = 128 + k;
    sumL += logsum[slot*2] + logsum[slot*2+1];
  }
  float lb = A[(size_t)N_*NPAD + N_];
  float yKy = CBORD - lb*lb;
  const float LOG2PI = 1.8378770664093453f;
  float Aterm = 0.5f*(yKy + sumL + (float)N_*LOG2PI);
  float Bterm = sumB + 0.5f*(float)(M_*D_)*LOG2PI;
  out[0] = Aterm + Bterm;
}

// ============================================================================
// chain driver: {trsm; step} per k, panel rides inside k_step block0.
// ============================================================================
static void run_chain(float* A, size_t aS, int lda, int nblk,
                      float* Tinv, size_t tz, size_t tk, int invAll,
                      float* lgs, int slotBase, int limit, int nz,
                      hipStream_t stream) {
  int doInv0 = (invAll || nblk > 1) ? 1 : 0;
  k_init<<<dim3(1,1,nz),256,0,stream>>>(A,aS,lda,Tinv,tz,lgs,slotBase,limit,doInv0);
  for (int k = 0; k < nblk-1; ++k) {
    int m = nblk-1-k;
    k_trsm<<<dim3(2*m,1,nz),256,0,stream>>>(A,aS,lda,k, Tinv + (size_t)k*tk, tz);
    int q2 = 2*m, ntiles = q2*(q2+1)/2 - 3;
    if (ntiles < 0) ntiles = 0;
    int nbx = 1 + ntiles;
    int doInv = (invAll || (k+1 < nblk-1)) ? 1 : 0;
    k_step<<<dim3(nbx,1,nz),256,0,stream>>>(A,aS,lda, k+1,1,doInv, Tinv,tz,tk,
                                            lgs,slotBase,limit, (k+1)*2, q2, k*NB);
  }
}

extern "C" void kernel_launch(void* const* d_in, const int* in_sizes, int n_in,
                              void* d_out, int out_size, void* d_ws, size_t ws_size,
                              hipStream_t stream) {
  const float* X    = (const float*)d_in[0];
  const float* y    = (const float*)d_in[1];
  const float* Xbar = (const float*)d_in[2];
  const float* lgls = (const float*)d_in[3];
  const float* lgstd= (const float*)d_in[4];
  const float* lgnz = (const float*)d_in[5];
  const float* lls  = (const float*)d_in[6];
  const float* gstd = (const float*)d_in[7];
  const float* gnz  = (const float*)d_in[8];
  float* out = (float*)d_out;

  const size_t A_SZ   = (size_t)NPAD*NPAD;
  const size_t KS_SZ  = (size_t)N_*M_;
  const size_t KB_SZ  = (size_t)M_*M_;
  const size_t TKB_SZ = (size_t)4*NB*NB;
  const size_t TBG_SZ = (size_t)NB*NB;
  const size_t W_SZ   = (size_t)M_;
  const size_t LV_SZ  = (size_t)N_*D_;
  const size_t LOG_SZ = 1024;

  size_t need2 = (5*A_SZ + 4*(KS_SZ + KB_SZ + TKB_SZ + W_SZ) + 5*TBG_SZ
                  + LV_SZ + LOG_SZ + 1024);
  size_t per1  = A_SZ + KS_SZ + KB_SZ + TKB_SZ + TBG_SZ + W_SZ;
  size_t need1 = 4*per1 + LV_SZ + LOG_SZ + 256;

  if (ws_size >= need2 * sizeof(float)) {
    // ---------- merged mode: one 25-step lookahead chain over 5 matrices ----
    float* p = (float*)d_ws;
    float* A    = p; p += 5*A_SZ;
    float* KS   = p; p += 4*KS_SZ;
    float* Kb   = p; p += 4*KB_SZ;
    float* Tkb  = p; p += 4*TKB_SZ;
    float* Tbig = p; p += 5*TBG_SZ;
    float* wv   = p; p += 4*W_SZ;
    float* lv   = p; p += LV_SZ;
    float* lgs  = p; p += LOG_SZ;

    k_build_kb<<<dim3((M_*M_+255)/256,1,4),256,0,stream>>>(Xbar,lgls,lgstd,lgnz,Kb,KB_SZ,0);
    run_chain(Kb, KB_SZ, M_, MBLK, Tkb, TKB_SZ, (size_t)NB*NB, 1, lgs, 192, 0, 4, stream);
    k_fwdsub<<<dim3(1,1,4),256,0,stream>>>(Kb,KB_SZ,Tkb,TKB_SZ,lls,wv,W_SZ,0);
    k_build_kstar<<<dim3((N_*M_+255)/256,1,4),256,0,stream>>>(X,Xbar,lgls,lgstd,KS,KS_SZ,0);
    for (int J = 0; J < MBLK; ++J)
      k_csolve<<<dim3(N_/64,1,4),256,0,stream>>>(KS,KS_SZ,Kb,KB_SZ,Tkb,TKB_SZ,J);
    k_gemv_l<<<dim3(N_/4,1,4),256,0,stream>>>(KS,KS_SZ,wv,W_SZ,lv,0);
    k_kpost<<<dim3(NPAD/64,NPAD/64,4),256,0,stream>>>(X,lgls,lgstd,KS,KS_SZ,A,A_SZ,0);
    k_kfinal<<<dim3((NPAD*NPAD+255)/256,1,1),256,0,stream>>>(X,lv,y,gstd,gnz,A+4*A_SZ);
    run_chain(A, A_SZ, NPAD, NBLK, Tbig, TBG_SZ, 0, 0, lgs, 0, N_, 5, stream);
    k_finalize<<<1,64,0,stream>>>(A+4*A_SZ,lgs,out);
    return;
  }

  // ---------- small-ws fallback: sequential passes ----------
  bool batched = ws_size >= need1 * sizeof(float);
  int nz = batched ? 4 : 1;
  float* p = (float*)d_ws;
  float* A    = p; p += (size_t)nz*A_SZ;
  float* KS   = p; p += (size_t)nz*KS_SZ;
  float* Kb   = p; p += (size_t)nz*KB_SZ;
  float* Tkb  = p; p += (size_t)nz*TKB_SZ;
  float* Tbig = p; p += (size_t)nz*TBG_SZ;
  float* wv   = p; p += (size_t)nz*W_SZ;
  float* lv   = p; p += LV_SZ;
  float* lgs  = p; p += LOG_SZ;

  int npass = batched ? 1 : 4;
  for (int pass = 0; pass < npass; ++pass) {
    int dimBase  = batched ? 0 : pass;
    int slotBase = batched ? 0 : pass*32;
    k_build_kb<<<dim3((M_*M_+255)/256,1,nz),256,0,stream>>>(Xbar,lgls,lgstd,lgnz,Kb,KB_SZ,dimBase);
    run_chain(Kb, KB_SZ, M_, MBLK, Tkb, TKB_SZ, (size_t)NB*NB, 1, lgs, 192+slotBase, 0, nz, stream);
    k_fwdsub<<<dim3(1,1,nz),256,0,stream>>>(Kb,KB_SZ,Tkb,TKB_SZ,lls,wv,W_SZ,dimBase);
    k_build_kstar<<<dim3((N_*M_+255)/256,1,nz),256,0,stream>>>(X,Xbar,lgls,lgstd,KS,KS_SZ,dimBase);
    for (int J = 0; J < MBLK; ++J)
      k_csolve<<<dim3(N_/64,1,nz),256,0,stream>>>(KS,KS_SZ,Kb,KB_SZ,Tkb,TKB_SZ,J);
    k_gemv_l<<<dim3(N_/4,1,nz),256,0,stream>>>(KS,KS_SZ,wv,W_SZ,lv,dimBase);
    k_kpost<<<dim3(NPAD/64,NPAD/64,nz),256,0,stream>>>(X,lgls,lgstd,KS,KS_SZ,A,A_SZ,dimBase);
    run_chain(A, A_SZ, NPAD, NBLK, Tbig, TBG_SZ, 0, 0, lgs, slotBase, N_, nz, stream);
  }
  k_kfinal<<<dim3((NPAD*NPAD+255)/256,1,1),256,0,stream>>>(X,lv,y,gstd,gnz,A);
  run_chain(A, A_SZ, NPAD, NBLK, Tbig, TBG_SZ, 0, 0, lgs, 128, N_, 1, stream);
  k_finalize<<<1,64,0,stream>>>(A,lgs,out);
}

// Round 12
// 7714.225 us; speedup vs baseline: 1.9183x; 1.8676x over previous
//
#include <hip/hip_runtime.h>
#include <math.h>

#define N_   3072
#define D_   4
#define M_   512
#define NPAD 3200
#define NB   128
#define PW   32
#define NBLK (NPAD/NB)   // 25
#define MBLK (M_/NB)     // 4
#define JITTER_ 0.05f
#define CBORD 32768.0f
#define LTS  132         // padded LDS stride for LT (col-major LT[c*LTS+r])

// ============================================================================
// syrk128: A[gr0..+128, gc0..+128] -= P_r P_c^T over cols [k0,k0+128).
// 512 threads, 4x8 acc/thread, stride-132 staging (R4-proven engine).
// ============================================================================
__device__ void syrk128(float* A, int lda, int gr0, int gc0, int k0,
                        float* As, float* Bs) {
  const int tid = threadIdx.x;
  const int tx = tid & 15, ty = tid >> 4;   // tx 0..15 (x8 cols), ty 0..31 (x4 rows)
  float acc[4][8];
  #pragma unroll
  for (int i = 0; i < 4; ++i)
    #pragma unroll
    for (int u = 0; u < 8; ++u) acc[i][u] = 0.f;
  for (int ks = 0; ks < NB; ks += 32) {
    __syncthreads();
    for (int t = tid; t < 128*8; t += 512) {
      int r = t >> 3, q = t & 7;
      float4 v = *(const float4*)&A[(size_t)(gr0+r)*lda + k0 + ks + q*4];
      As[(q*4+0)*132+r]=v.x; As[(q*4+1)*132+r]=v.y;
      As[(q*4+2)*132+r]=v.z; As[(q*4+3)*132+r]=v.w;
      float4 w = *(const float4*)&A[(size_t)(gc0+r)*lda + k0 + ks + q*4];
      Bs[(q*4+0)*132+r]=w.x; Bs[(q*4+1)*132+r]=w.y;
      Bs[(q*4+2)*132+r]=w.z; Bs[(q*4+3)*132+r]=w.w;
    }
    __syncthreads();
    #pragma unroll
    for (int kk = 0; kk < 32; ++kk) {
      float a[4], b[8];
      *(float4*)a      = *(const float4*)&As[kk*132 + ty*4];
      *(float4*)&b[0]  = *(const float4*)&Bs[kk*132 + tx*8];
      *(float4*)&b[4]  = *(const float4*)&Bs[kk*132 + tx*8 + 4];
      #pragma unroll
      for (int i = 0; i < 4; ++i)
        #pragma unroll
        for (int u = 0; u < 8; ++u) acc[i][u] += a[i]*b[u];
    }
  }
  #pragma unroll
  for (int i = 0; i < 4; ++i) {
    size_t off = (size_t)(gr0 + ty*4 + i)*lda + gc0 + tx*8;
    float4 v0 = *(const float4*)&A[off];
    float4 v1 = *(const float4*)&A[off + 4];
    v0.x -= acc[i][0]; v0.y -= acc[i][1]; v0.z -= acc[i][2]; v0.w -= acc[i][3];
    v1.x -= acc[i][4]; v1.y -= acc[i][5]; v1.z -= acc[i][6]; v1.w -= acc[i][7];
    *(float4*)&A[off]     = v0;
    *(float4*)&A[off + 4] = v1;
  }
}

// presub: LT -= P_sr * P_sc^T over panel cols p0.., rows j0+s*64. (R5-proven)
__device__ void presub64(const float* A, int lda, int j0, int p0, int sr, int sc,
                         int valid, float* As, float* Bs, float* LT_, int lt) {
  const int tx = lt & 15, ty = lt >> 4;
  float acc[4][4];
  #pragma unroll
  for (int i=0;i<4;++i){acc[i][0]=0.f;acc[i][1]=0.f;acc[i][2]=0.f;acc[i][3]=0.f;}
  for (int ks = 0; ks < NB; ks += 32) {
    __syncthreads();
    if (valid) {
      for (int t = lt; t < 64*8; t += 256) {
        int rr = t >> 3, qq = t & 7;
        float4 v = *(const float4*)&A[(size_t)(j0+sr*64+rr)*lda + p0 + ks + qq*4];
        As[(qq*4+0)*68+rr]=v.x; As[(qq*4+1)*68+rr]=v.y;
        As[(qq*4+2)*68+rr]=v.z; As[(qq*4+3)*68+rr]=v.w;
        float4 w = *(const float4*)&A[(size_t)(j0+sc*64+rr)*lda + p0 + ks + qq*4];
        Bs[(qq*4+0)*68+rr]=w.x; Bs[(qq*4+1)*68+rr]=w.y;
        Bs[(qq*4+2)*68+rr]=w.z; Bs[(qq*4+3)*68+rr]=w.w;
      }
    }
    __syncthreads();
    if (valid) {
      #pragma unroll
      for (int kk = 0; kk < 32; ++kk) {
        float a[4], b[4];
        *(float4*)a = *(const float4*)&As[kk*68 + ty*4];
        *(float4*)b = *(const float4*)&Bs[kk*68 + tx*4];
        #pragma unroll
        for (int i=0;i<4;++i)
          #pragma unroll
          for (int u=0;u<4;++u) acc[i][u] += a[i]*b[u];
      }
    }
  }
  if (valid) {
    #pragma unroll
    for (int i=0;i<4;++i)
      #pragma unroll
      for (int u=0;u<4;++u) {
        int rr = sr*64 + ty*4 + i, cc = sc*64 + tx*4 + u;
        if (cc <= rr) LT_[cc*LTS + rr] -= acc[i][u];
      }
  }
}

// ============================================================================
// potrf (+presub of panel j0-NB) (+blocked inverse). 512 threads. (R5-proven)
// ============================================================================
__device__ void potrf_duty(float* A, int lda, int b, int presub, int doInv,
                           float* Tinv, float* logsum, int slot, int limit,
                           float* LT_, float* SM_, float* pivd_) {
  const int tid = threadIdx.x;
  const int j0 = b * NB;
  for (int t = tid; t < NB*NB; t += 512) {
    int r = t >> 7, c = t & 127;
    float v = 0.f;
    if (c <= r) v = A[(size_t)(j0+r)*lda + (j0+c)];
    LT_[c*LTS + r] = v;
  }
  if (presub) {
    int half = tid >> 8, lt = tid & 255;
    float* As = SM_ + half*4352; float* Bs = As + 2176;
    const int p0 = j0 - NB;
    presub64(A, lda, j0, p0, half, 0, 1, As, Bs, LT_, lt);
    presub64(A, lda, j0, p0, 1, 1, half==0 ? 1 : 0, As, Bs, LT_, lt);
  }
  __syncthreads();
  #pragma unroll
  for (int p = 0; p < 4; ++p) {
    const int pc0 = p*PW, pc1 = pc0 + PW;
    for (int j = pc0; j < pc1; ++j) {
      float dd = fmaxf(LT_[j*LTS + j], 1e-30f);
      if (tid == 0) pivd_[j] = dd;
      float rd = 1.0f / dd;
      int wn = pc1 - 1 - j;
      for (int t = tid; t < wn*NB; t += 512) {
        int c = j + 1 + (t >> 7);
        int i = t & 127;
        if (i >= c) LT_[c*LTS + i] -= LT_[j*LTS + i] * LT_[j*LTS + c] * rd;
      }
      __syncthreads();
    }
    for (int t = tid; t < PW*NB; t += 512) {
      int jc = pc0 + (t >> 7);
      int i  = t & 127;
      float dd = pivd_[jc];
      if (i > jc)       LT_[jc*LTS + i] *= rsqrtf(dd);
      else if (i == jc) LT_[jc*LTS + i] = sqrtf(dd);
    }
    __syncthreads();
    if (pc1 < NB) {
      const int rem = NB - pc1, g4 = rem >> 2;
      for (int t = tid; t < g4*g4; t += 512) {
        int tr = t / g4, tc = t - tr*g4;
        if (tc > tr) continue;
        int i0 = pc1 + tr*4, c0 = pc1 + tc*4;
        float acc2[4][4];
        #pragma unroll
        for (int i=0;i<4;++i){acc2[i][0]=0.f;acc2[i][1]=0.f;acc2[i][2]=0.f;acc2[i][3]=0.f;}
        #pragma unroll
        for (int jj = 0; jj < PW; ++jj) {
          float av[4], bv[4];
          *(float4*)av = *(const float4*)&LT_[(pc0+jj)*LTS + i0];
          *(float4*)bv = *(const float4*)&LT_[(pc0+jj)*LTS + c0];
          #pragma unroll
          for (int i=0;i<4;++i)
            #pragma unroll
            for (int u=0;u<4;++u) acc2[i][u] += av[i]*bv[u];
        }
        #pragma unroll
        for (int i=0;i<4;++i)
          #pragma unroll
          for (int u=0;u<4;++u) {
            int rr = i0+i, cc = c0+u;
            if (cc <= rr) LT_[cc*LTS + rr] -= acc2[i][u];
          }
      }
      __syncthreads();
    }
  }
  for (int t = tid; t < NB*NB; t += 512) {
    int r = t >> 7, c = t & 127;
    if (c <= r) A[(size_t)(j0+r)*lda + (j0+c)] = LT_[c*LTS + r];
  }
  {
    float lg = 0.f;
    if (tid < NB) {
      int g = j0 + tid;
      if (g < limit) lg = 0.5f * logf(pivd_[tid]);
    }
    for (int o = 32; o; o >>= 1) lg += __shfl_down(lg, o);
    int wv = tid >> 6;
    if ((tid & 63) == 0 && wv < 2) logsum[slot*2 + wv] = lg;
  }
  if (!doInv) return;
  float* Wp = SM_;
  float* Tt = SM_ + 10240;
  for (int t = tid; t < 4*1024; t += 512) {
    int I = t >> 10, e = t & 1023;
    int r = e >> 5, c = e & 31;
    Wp[(I*(I+1)/2 + I)*1024 + e] = (r == c) ? 1.f : 0.f;
  }
  __syncthreads();
  {
    int wI = tid >> 7;
    int lane = tid & 127;
    float* Rb = &Wp[(wI*(wI+1)/2 + wI)*1024];
    for (int j = 0; j < 32; ++j) {
      float dinv = 1.0f / LT_[(wI*32+j)*LTS + (wI*32+j)];
      for (int t = lane; t < 1024; t += 128) {
        int i = t >> 5, c = t & 31;
        if (i > j && c <= j)
          Rb[i*32 + c] -= LT_[(wI*32+j)*LTS + (wI*32+i)] * Rb[j*32 + c] * dinv;
      }
      __syncthreads();
    }
    for (int t = lane; t < 1024; t += 128) {
      int i = t >> 5, c = t & 31;
      if (c <= i) Rb[i*32 + c] *= 1.0f / LT_[(wI*32+i)*LTS + (wI*32+i)];
    }
    __syncthreads();
  }
  #pragma unroll
  for (int dist = 1; dist < 4; ++dist) {
    const int nb = 4 - dist;
    for (int t = tid; t < nb*1024; t += 512) {
      int bb = t >> 10, e = t & 1023;
      int r = e >> 5, c = e & 31;
      int J = bb, I = bb + dist;
      float s = 0.f;
      for (int K = J; K < I; ++K) {
        const float* Wkj = &Wp[(K*(K+1)/2 + J)*1024];
        #pragma unroll
        for (int k = 0; k < 32; ++k)
          s += LT_[(K*32+k)*LTS + (I*32+r)] * Wkj[k*32 + c];
      }
      Tt[bb*1024 + e] = s;
    }
    __syncthreads();
    for (int t = tid; t < nb*1024; t += 512) {
      int bb = t >> 10, e = t & 1023;
      int r = e >> 5, c = e & 31;
      int J = bb, I = bb + dist;
      const float* Wii = &Wp[(I*(I+1)/2 + I)*1024];
      float s = 0.f;
      #pragma unroll
      for (int k = 0; k < 32; ++k)
        s += Wii[r*32 + k] * Tt[bb*1024 + k*32 + c];
      Wp[(I*(I+1)/2 + J)*1024 + e] = -s;
    }
    __syncthreads();
  }
  for (int t = tid; t < NB*32; t += 512) {
    int i = t >> 5, c4 = (t & 31) * 4;
    int I = i >> 5, J = c4 >> 5;
    float4 v;
    if (J <= I) {
      const float* Wij = &Wp[(I*(I+1)/2 + J)*1024 + (i & 31)*32 + (c4 & 31)];
      v = *(const float4*)Wij;
    } else v = make_float4(0.f, 0.f, 0.f, 0.f);
    *(float4*)&Tinv[i*NB + c4] = v;
  }
}

// ============================================================================
// k_step: block0 = potrf(+presub,+inv) of block bpot; blocks 1..T-1 = one
// 128x128 syrk tile each over trailing blocks (skip (0,0) diag = presub'd).
// ============================================================================
__global__ __launch_bounds__(512, 1)
void k_step(float* Abase, size_t aStride, int lda, int bpot, int presub, int doInv,
            float* TinvBase, size_t tStrideZ, size_t tStrideK,
            float* logsum, int slotBase, int limit,
            int R0, int T, int k0) {
  __shared__ __align__(16) float LT[128*LTS];
  __shared__ __align__(16) float SM[13312];
  __shared__ float pivd[NB];
  const int z = blockIdx.z;
  float* A = Abase + (size_t)z*aStride;

  if (blockIdx.x == 0) {
    potrf_duty(A, lda, bpot, presub, doInv,
               TinvBase + (size_t)z*tStrideZ + (size_t)bpot*tStrideK,
               logsum, slotBase + z*32 + bpot, limit, LT, SM, pivd);
    return;
  }
  int idxp = blockIdx.x;     // 1..T-1, lower-tri index (I(I+1)/2 + J), skip (0,0)
  int r = (int)((sqrtf(8.f*(float)idxp + 1.f) - 1.f)*0.5f);
  while ((r+1)*(r+2)/2 <= idxp) ++r;
  while (r*(r+1)/2 > idxp) --r;
  int c = idxp - r*(r+1)/2;
  syrk128(A, lda, (R0+r)*NB, (R0+c)*NB, k0, SM, SM + 4224);
}

// ---------------- trsm: L21 = A21 * Tinv^T (R3-proven) ----------------
__global__ __launch_bounds__(256)
void k_trsm(float* Abase, size_t aStride, int lda, int kblk,
            const float* TinvBase, size_t tStride) {
  __shared__ float As[32*68];
  __shared__ float Ts[32*132];
  const int tid = threadIdx.x;
  float* A = Abase + (size_t)blockIdx.z * aStride;
  const float* Tinv = TinvBase + (size_t)blockIdx.z * tStride;
  const int k0 = kblk * NB;
  const int row0 = k0 + NB + blockIdx.x * 64;
  const int tx = tid & 15, ty = tid >> 4;
  float acc[4][8];
  #pragma unroll
  for (int i = 0; i < 4; ++i)
    #pragma unroll
    for (int u = 0; u < 8; ++u) acc[i][u] = 0.f;
  for (int ks = 0; ks < NB; ks += 32) {
    for (int t = tid; t < 64*8; t += 256) {
      int r = t >> 3, q = t & 7;
      float4 v = *(const float4*)&A[(size_t)(row0 + r)*lda + k0 + ks + q*4];
      As[(q*4+0)*68 + r] = v.x; As[(q*4+1)*68 + r] = v.y;
      As[(q*4+2)*68 + r] = v.z; As[(q*4+3)*68 + r] = v.w;
    }
    for (int t = tid; t < 128*8; t += 256) {
      int c = t >> 3, q = t & 7;
      float4 v = *(const float4*)&Tinv[c*NB + ks + q*4];
      Ts[(q*4+0)*132 + c] = v.x; Ts[(q*4+1)*132 + c] = v.y;
      Ts[(q*4+2)*132 + c] = v.z; Ts[(q*4+3)*132 + c] = v.w;
    }
    __syncthreads();
    #pragma unroll
    for (int kk = 0; kk < 32; ++kk) {
      float a[4], b[8];
      *(float4*)a      = *(const float4*)&As[kk*68 + ty*4];
      *(float4*)&b[0]  = *(const float4*)&Ts[kk*132 + tx*8];
      *(float4*)&b[4]  = *(const float4*)&Ts[kk*132 + tx*8 + 4];
      #pragma unroll
      for (int i = 0; i < 4; ++i)
        #pragma unroll
        for (int u = 0; u < 8; ++u) acc[i][u] += a[i]*b[u];
    }
    __syncthreads();
  }
  #pragma unroll
  for (int i = 0; i < 4; ++i) {
    int r = row0 + ty*4 + i;
    *(float4*)&A[(size_t)r*lda + k0 + tx*8]     = make_float4(acc[i][0],acc[i][1],acc[i][2],acc[i][3]);
    *(float4*)&A[(size_t)r*lda + k0 + tx*8 + 4] = make_float4(acc[i][4],acc[i][5],acc[i][6],acc[i][7]);
  }
}

// ---------------- builders / solves / epilogue (proven, unchanged) ----------
__global__ __launch_bounds__(256)
void k_build_kb(const float* Xbar, const float* lsp, const float* stdp, const float* noisep,
                float* KbBase, size_t kbStride, int dimBase) {
  int z = blockIdx.z, d = dimBase + z;
  float* Kb = KbBase + (size_t)z*kbStride;
  int idx = blockIdx.x*256 + threadIdx.x;
  if (idx >= M_*M_) return;
  int i = idx >> 9, j = idx & 511;
  float ls = lsp[d], sd = stdp[d], nz = noisep[d];
  float df = Xbar[i*D_ + d] - Xbar[j*D_ + d];
  float v = sd*sd*expf(-0.5f*df*df/(ls*ls));
  if (i == j) v += nz*nz;
  Kb[idx] = v;
}

__global__ __launch_bounds__(256)
void k_build_kstar(const float* X, const float* Xbar, const float* lsp, const float* stdp,
                   float* KSBase, size_t ksStride, int dimBase) {
  int z = blockIdx.z, d = dimBase + z;
  float* KS = KSBase + (size_t)z*ksStride;
  int idx = blockIdx.x*256 + threadIdx.x;
  if (idx >= N_*M_) return;
  int i = idx >> 9, j = idx & 511;
  float ls = lsp[d], sd = stdp[d];
  float df = X[i*D_ + d] - Xbar[j*D_ + d];
  KS[idx] = sd*sd*expf(-0.5f*df*df/(ls*ls));
}

__global__ __launch_bounds__(256)
void k_csolve(float* CBase, size_t cStride, const float* KbBase, size_t kbStride,
              const float* TinvKbBase, size_t tkbStride, int J) {
  __shared__ float sm[12672];
  const int tid = threadIdx.x;
  float* C = CBase + (size_t)blockIdx.z*cStride;
  const float* L = KbBase + (size_t)blockIdx.z*kbStride;
  const float* Tinv = TinvKbBase + (size_t)blockIdx.z*tkbStride + (size_t)J*NB*NB;
  const int row0 = blockIdx.x*64;
  const int tx = tid & 15, ty = tid >> 4;
  float* As = sm; float* Ls = sm + 2176;
  float* Xs = sm; float* Ts = sm + 8448;
  float acc[4][8];
  #pragma unroll
  for (int i=0;i<4;++i) {
    const float* p = &C[(size_t)(row0+ty*4+i)*M_ + J*NB + tx*8];
    float4 v0 = *(const float4*)p, v1 = *(const float4*)(p+4);
    acc[i][0]=v0.x; acc[i][1]=v0.y; acc[i][2]=v0.z; acc[i][3]=v0.w;
    acc[i][4]=v1.x; acc[i][5]=v1.y; acc[i][6]=v1.z; acc[i][7]=v1.w;
  }
  for (int P = 0; P < J; ++P) {
    for (int ks = 0; ks < NB; ks += 32) {
      __syncthreads();
      for (int t = tid; t < 64*8; t += 256) {
        int r = t >> 3, q = t & 7;
        float4 v = *(const float4*)&C[(size_t)(row0+r)*M_ + P*NB + ks + q*4];
        As[(q*4+0)*68+r]=v.x; As[(q*4+1)*68+r]=v.y; As[(q*4+2)*68+r]=v.z; As[(q*4+3)*68+r]=v.w;
      }
      for (int t = tid; t < 128*8; t += 256) {
        int c = t >> 3, q = t & 7;
        float4 v = *(const float4*)&L[(size_t)(J*NB+c)*M_ + P*NB + ks + q*4];
        Ls[(q*4+0)*132+c]=v.x; Ls[(q*4+1)*132+c]=v.y; Ls[(q*4+2)*132+c]=v.z; Ls[(q*4+3)*132+c]=v.w;
      }
      __syncthreads();
      #pragma unroll
      for (int kk = 0; kk < 32; ++kk) {
        float a[4], b[8];
        *(float4*)a     = *(const float4*)&As[kk*68 + ty*4];
        *(float4*)&b[0] = *(const float4*)&Ls[kk*132 + tx*8];
        *(float4*)&b[4] = *(const float4*)&Ls[kk*132 + tx*8 + 4];
        #pragma unroll
        for (int i=0;i<4;++i)
          #pragma unroll
          for (int u=0;u<8;++u) acc[i][u] -= a[i]*b[u];
      }
    }
  }
  __syncthreads();
  #pragma unroll
  for (int i=0;i<4;++i)
    #pragma unroll
    for (int u=0;u<8;++u) Xs[(ty*4+i)*132 + tx*8+u] = acc[i][u];
  #pragma unroll
  for (int i=0;i<4;++i)
    #pragma unroll
    for (int u=0;u<8;++u) acc[i][u] = 0.f;
  for (int ms = 0; ms < NB; ms += 32) {
    for (int t = tid; t < 128*8; t += 256) {
      int c = t >> 3, q = t & 7;
      float4 v = *(const float4*)&Tinv[c*NB + ms + q*4];
      Ts[(q*4+0)*132+c]=v.x; Ts[(q*4+1)*132+c]=v.y; Ts[(q*4+2)*132+c]=v.z; Ts[(q*4+3)*132+c]=v.w;
    }
    __syncthreads();
    #pragma unroll
    for (int mm = 0; mm < 32; ++mm) {
      float a[4], b[8];
      a[0]=Xs[(ty*4+0)*132+ms+mm]; a[1]=Xs[(ty*4+1)*132+ms+mm];
      a[2]=Xs[(ty*4+2)*132+ms+mm]; a[3]=Xs[(ty*4+3)*132+ms+mm];
      *(float4*)&b[0] = *(const float4*)&Ts[mm*132 + tx*8];
      *(float4*)&b[4] = *(const float4*)&Ts[mm*132 + tx*8 + 4];
      #pragma unroll
      for (int i=0;i<4;++i)
        #pragma unroll
        for (int u=0;u<8;++u) acc[i][u] += a[i]*b[u];
    }
    __syncthreads();
  }
  #pragma unroll
  for (int i=0;i<4;++i) {
    float* p = &C[(size_t)(row0+ty*4+i)*M_ + J*NB + tx*8];
    *(float4*)p     = make_float4(acc[i][0],acc[i][1],acc[i][2],acc[i][3]);
    *(float4*)(p+4) = make_float4(acc[i][4],acc[i][5],acc[i][6],acc[i][7]);
  }
}

__global__ __launch_bounds__(256)
void k_fwdsub(const float* KbBase, size_t kbStride,
              const float* TkbBase, size_t tkbStride,
              const float* lls, float* wBase, size_t wStride, int dimBase) {
  __shared__ float w[M_];
  __shared__ float tv[NB];
  __shared__ float red[256];
  int z = blockIdx.z, d = dimBase + z;
  const float* L = KbBase + (size_t)z*kbStride;
  const float* Tk = TkbBase + (size_t)z*tkbStride;
  float* wout = wBase + (size_t)z*wStride;
  const int tid = threadIdx.x;
  for (int i = tid; i < M_; i += 256) w[i] = logf(fabsf(lls[i*D_ + d]));
  __syncthreads();
  const int r = tid >> 1, h = tid & 1;
  for (int J = 0; J < 4; ++J) {
    float s = 0.f;
    int half = (J*NB) >> 1;
    for (int k = h*half; k < (h+1)*half; k += 4) {
      float4 lv = *(const float4*)&L[(size_t)(J*NB + r)*M_ + k];
      s += lv.x*w[k] + lv.y*w[k+1] + lv.z*w[k+2] + lv.w*w[k+3];
    }
    red[tid] = s;
    __syncthreads();
    if (h == 0) tv[r] = w[J*NB + r] - red[2*r] - red[2*r+1];
    __syncthreads();
    const float* Ti = Tk + (size_t)J*NB*NB;
    s = 0.f;
    for (int k = h*64; k < h*64 + 64; k += 4) {
      float4 tw = *(const float4*)&Ti[r*NB + k];
      s += tw.x*tv[k] + tw.y*tv[k+1] + tw.z*tv[k+2] + tw.w*tv[k+3];
    }
    red[tid] = s;
    __syncthreads();
    if (h == 0) w[J*NB + r] = red[2*r] + red[2*r+1];
    __syncthreads();
  }
  for (int i = tid; i < M_; i += 256) wout[i] = w[i];
}

__global__ __launch_bounds__(256)
void k_gemv_l(const float* CBase, size_t cStride, const float* wBase, size_t wStride,
              float* lvec, int dimBase) {
  int z = blockIdx.z, d = dimBase + z;
  const float* C = CBase + (size_t)z*cStride;
  const float* w = wBase + (size_t)z*wStride;
  __shared__ float ws[M_];
  for (int i = threadIdx.x; i < M_; i += 256) ws[i] = w[i];
  __syncthreads();
  int wid = threadIdx.x >> 6, lane = threadIdx.x & 63;
  int row = blockIdx.x*4 + wid;
  if (row >= N_) return;
  float s = 0.f;
  const float* cr = &C[(size_t)row*M_];
  for (int k = lane; k < M_; k += 64) s += cr[k]*ws[k];
  for (int o = 32; o; o >>= 1) s += __shfl_down(s, o);
  if (lane == 0) lvec[row*D_ + d] = expf(s);
}

__global__ __launch_bounds__(256)
void k_kpost(const float* X, const float* lsp, const float* stdp,
             const float* CBase, size_t cStride,
             float* Abase, size_t aStride, int dimBase) {
  if (blockIdx.y > blockIdx.x) return;
  __shared__ float As[32*68];
  __shared__ float Bs[32*68];
  int z = blockIdx.z, d = dimBase + z;
  const float* C = CBase + (size_t)z*cStride;
  float* A = Abase + (size_t)z*aStride;
  const int row0 = blockIdx.x*64, col0 = blockIdx.y*64;
  const int tid = threadIdx.x, tx = tid & 15, ty = tid >> 4;
  float acc[4][4];
  #pragma unroll
  for (int i=0;i<4;++i) { acc[i][0]=0.f;acc[i][1]=0.f;acc[i][2]=0.f;acc[i][3]=0.f; }
  if (row0 < N_) {
    for (int ks = 0; ks < M_; ks += 32) {
      for (int t = tid; t < 64*8; t += 256) {
        int r = t >> 3, q = t & 7;
        float4 v = *(const float4*)&C[(size_t)(row0+r)*M_ + ks + q*4];
        As[(q*4+0)*68+r]=v.x; As[(q*4+1)*68+r]=v.y; As[(q*4+2)*68+r]=v.z; As[(q*4+3)*68+r]=v.w;
        float4 w2 = *(const float4*)&C[(size_t)(col0+r)*M_ + ks + q*4];
        Bs[(q*4+0)*68+r]=w2.x; Bs[(q*4+1)*68+r]=w2.y; Bs[(q*4+2)*68+r]=w2.z; Bs[(q*4+3)*68+r]=w2.w;
      }
      __syncthreads();
      #pragma unroll
      for (int kk=0; kk<32; ++kk) {
        float a[4], b[4];
        *(float4*)a = *(const float4*)&As[kk*68 + ty*4];
        *(float4*)b = *(const float4*)&Bs[kk*68 + tx*4];
        #pragma unroll
        for (int i=0;i<4;++i)
          #pragma unroll
          for (int u=0;u<4;++u) acc[i][u] += a[i]*b[u];
      }
      __syncthreads();
    }
  }
  float ls = lsp[d], sd = stdp[d];
  float inv2 = -0.5f/(ls*ls), s2 = sd*sd;
  #pragma unroll
  for (int i=0;i<4;++i) {
    int gi = row0 + ty*4 + i;
    float xi = (gi < N_) ? X[gi*D_ + d] : 0.f;
    #pragma unroll
    for (int u=0;u<4;++u) {
      int gj = col0 + tx*4 + u;
      float v;
      if (gi < N_ && gj < N_) {
        float df = xi - X[gj*D_ + d];
        v = s2*expf(inv2*df*df) - acc[i][u];
        if (gi == gj) v += JITTER_;
      } else {
        v = (gi == gj) ? 1.f : 0.f;
      }
      A[(size_t)gi*NPAD + gj] = v;
    }
  }
}

__global__ __launch_bounds__(256)
void k_kfinal(const float* X, const float* lvec, const float* y,
              const float* gstd, const float* gnoise, float* A) {
  int idx = blockIdx.x*256 + threadIdx.x;
  if (idx >= NPAD*NPAD) return;
  int gi = idx / NPAD, gj = idx - (idx/NPAD)*NPAD;
  float v;
  if (gi < N_ && gj < N_) {
    float gv = gstd[0]*gstd[0];
    float prod = 1.f, s = 0.f;
    #pragma unroll
    for (int d = 0; d < D_; ++d) {
      float l1 = lvec[gi*D_ + d], l2 = lvec[gj*D_ + d];
      float lsq = l1*l1 + l2*l2;
      prod *= 2.f*l1*l2/lsq;
      float df = X[gi*D_ + d] - X[gj*D_ + d];
      s += df*df/lsq;
    }
    v = gv * sqrtf(prod) * expf(-s);
    if (gi == gj) v += gnoise[0]*gnoise[0];
  } else if (gi == N_ && gj < N_) v = y[gj];
  else if (gj == N_ && gi < N_) v = y[gi];
  else if (gi == N_ && gj == N_) v = CBORD;
  else v = (gi == gj) ? 1.f : 0.f;
  A[idx] = v;
}

__global__ void k_finalize(const float* A, const float* logsum, float* out) {
  if (threadIdx.x != 0 || blockIdx.x != 0) return;
  float sumB = 0.f;
  for (int z = 0; z < 4; ++z)
    for (int k = 0; k < NBLK; ++k) {
      int slot = z*32 + k;
      sumB += logsum[slot*2] + logsum[slot*2+1];
    }
  float sumL = 0.f;
  for (int k = 0; k < NBLK; ++k) {
    int slot = 128 + k;
    sumL += logsum[slot*2] + logsum[slot*2+1];
  }
  float lb = A[(size_t)N_*NPAD + N_];
  float yKy = CBORD - lb*lb;
  const float LOG2PI = 1.8378770664093453f;
  float Aterm = 0.5f*(yKy + sumL + (float)N_*LOG2PI);
  float Bterm = sumB + 0.5f*(float)(M_*D_)*LOG2PI;
  out[0] = Aterm + Bterm;
}

// ============================================================================
// chain driver: {trsm; step} per k, potrf rides inside k_step block0.
// ============================================================================
static void run_chain(float* A, size_t aS, int lda, int nblk,
                      float* Tinv, size_t tz, size_t tk, int invAll,
                      float* lgs, int slotBase, int limit, int nz,
                      hipStream_t stream) {
  int doInv0 = (invAll || nblk > 1) ? 1 : 0;
  k_step<<<dim3(1,1,nz),512,0,stream>>>(A,aS,lda, 0,0,doInv0, Tinv,tz,tk,
                                        lgs,slotBase,limit, 0,0,0);
  for (int k = 0; k < nblk-1; ++k) {
    int m = nblk-1-k;
    k_trsm<<<dim3(2*m,1,nz),256,0,stream>>>(A,aS,lda,k, Tinv + (size_t)k*tk, tz);
    int T = m*(m+1)/2;
    int doInv = (invAll || (k+1 < nblk-1)) ? 1 : 0;
    k_step<<<dim3(T,1,nz),512,0,stream>>>(A,aS,lda, k+1,1,doInv, Tinv,tz,tk,
                                          lgs,slotBase,limit, k+1, T, k*NB);
  }
}

extern "C" void kernel_launch(void* const* d_in, const int* in_sizes, int n_in,
                              void* d_out, int out_size, void* d_ws, size_t ws_size,
                              hipStream_t stream) {
  const float* X    = (const float*)d_in[0];
  const float* y    = (const float*)d_in[1];
  const float* Xbar = (const float*)d_in[2];
  const float* lgls = (const float*)d_in[3];
  const float* lgstd= (const float*)d_in[4];
  const float* lgnz = (const float*)d_in[5];
  const float* lls  = (const float*)d_in[6];
  const float* gstd = (const float*)d_in[7];
  const float* gnz  = (const float*)d_in[8];
  float* out = (float*)d_out;

  const size_t A_SZ   = (size_t)NPAD*NPAD;
  const size_t KS_SZ  = (size_t)N_*M_;
  const size_t KB_SZ  = (size_t)M_*M_;
  const size_t TKB_SZ = (size_t)4*NB*NB;
  const size_t TBG_SZ = (size_t)NB*NB;
  const size_t W_SZ   = (size_t)M_;
  const size_t LV_SZ  = (size_t)N_*D_;
  const size_t LOG_SZ = 1024;

  size_t need2 = (5*A_SZ + 4*(KS_SZ + KB_SZ + TKB_SZ + W_SZ) + 5*TBG_SZ
                  + LV_SZ + LOG_SZ + 1024);
  size_t per1  = A_SZ + KS_SZ + KB_SZ + TKB_SZ + TBG_SZ + W_SZ;
  size_t need1 = 4*per1 + LV_SZ + LOG_SZ + 256;

  if (ws_size >= need2 * sizeof(float)) {
    // ---------- merged mode: one 25-step lookahead chain over 5 matrices ----
    float* p = (float*)d_ws;
    float* A    = p; p += 5*A_SZ;
    float* KS   = p; p += 4*KS_SZ;
    float* Kb   = p; p += 4*KB_SZ;
    float* Tkb  = p; p += 4*TKB_SZ;
    float* Tbig = p; p += 5*TBG_SZ;
    float* wv   = p; p += 4*W_SZ;
    float* lv   = p; p += LV_SZ;
    float* lgs  = p; p += LOG_SZ;

    k_build_kb<<<dim3((M_*M_+255)/256,1,4),256,0,stream>>>(Xbar,lgls,lgstd,lgnz,Kb,KB_SZ,0);
    run_chain(Kb, KB_SZ, M_, MBLK, Tkb, TKB_SZ, (size_t)NB*NB, 1, lgs, 192, 0, 4, stream);
    k_fwdsub<<<dim3(1,1,4),256,0,stream>>>(Kb,KB_SZ,Tkb,TKB_SZ,lls,wv,W_SZ,0);
    k_build_kstar<<<dim3((N_*M_+255)/256,1,4),256,0,stream>>>(X,Xbar,lgls,lgstd,KS,KS_SZ,0);
    for (int J = 0; J < MBLK; ++J)
      k_csolve<<<dim3(N_/64,1,4),256,0,stream>>>(KS,KS_SZ,Kb,KB_SZ,Tkb,TKB_SZ,J);
    k_gemv_l<<<dim3(N_/4,1,4),256,0,stream>>>(KS,KS_SZ,wv,W_SZ,lv,0);
    k_kpost<<<dim3(NPAD/64,NPAD/64,4),256,0,stream>>>(X,lgls,lgstd,KS,KS_SZ,A,A_SZ,0);
    k_kfinal<<<dim3((NPAD*NPAD+255)/256,1,1),256,0,stream>>>(X,lv,y,gstd,gnz,A+4*A_SZ);
    run_chain(A, A_SZ, NPAD, NBLK, Tbig, TBG_SZ, 0, 0, lgs, 0, N_, 5, stream);
    k_finalize<<<1,64,0,stream>>>(A+4*A_SZ,lgs,out);
    return;
  }

  // ---------- small-ws fallback: sequential passes ----------
  bool batched = ws_size >= need1 * sizeof(float);
  int nz = batched ? 4 : 1;
  float* p = (float*)d_ws;
  float* A    = p; p += (size_t)nz*A_SZ;
  float* KS   = p; p += (size_t)nz*KS_SZ;
  float* Kb   = p; p += (size_t)nz*KB_SZ;
  float* Tkb  = p; p += (size_t)nz*TKB_SZ;
  float* Tbig = p; p += (size_t)nz*TBG_SZ;
  float* wv   = p; p += (size_t)nz*W_SZ;
  float* lv   = p; p += LV_SZ;
  float* lgs  = p; p += LOG_SZ;

  int npass = batched ? 1 : 4;
  for (int pass = 0; pass < npass; ++pass) {
    int dimBase  = batched ? 0 : pass;
    int slotBase = batched ? 0 : pass*32;
    k_build_kb<<<dim3((M_*M_+255)/256,1,nz),256,0,stream>>>(Xbar,lgls,lgstd,lgnz,Kb,KB_SZ,dimBase);
    run_chain(Kb, KB_SZ, M_, MBLK, Tkb, TKB_SZ, (size_t)NB*NB, 1, lgs, 192+slotBase, 0, nz, stream);
    k_fwdsub<<<dim3(1,1,nz),256,0,stream>>>(Kb,KB_SZ,Tkb,TKB_SZ,lls,wv,W_SZ,dimBase);
    k_build_kstar<<<dim3((N_*M_+255)/256,1,nz),256,0,stream>>>(X,Xbar,lgls,lgstd,KS,KS_SZ,dimBase);
    for (int J = 0; J < MBLK; ++J)
      k_csolve<<<dim3(N_/64,1,nz),256,0,stream>>>(KS,KS_SZ,Kb,KB_SZ,Tkb,TKB_SZ,J);
    k_gemv_l<<<dim3(N_/4,1,nz),256,0,stream>>>(KS,KS_SZ,wv,W_SZ,lv,dimBase);
    k_kpost<<<dim3(NPAD/64,NPAD/64,nz),256,0,stream>>>(X,lgls,lgstd,KS,KS_SZ,A,A_SZ,dimBase);
    run_chain(A, A_SZ, NPAD, NBLK, Tbig, TBG_SZ, 0, 0, lgs, slotBase, N_, nz, stream);
  }
  k_kfinal<<<dim3((NPAD*NPAD+255)/256,1,1),256,0,stream>>>(X,lv,y,gstd,gnz,A);
  run_chain(A, A_SZ, NPAD, NBLK, Tbig, TBG_SZ, 0, 0, lgs, 128, N_, 1, stream);
  k_finalize<<<1,64,0,stream>>>(A,lgs,out);
}